// Round 1
// baseline (790.387 us; speedup 1.0000x reference)
//
#include <hip/hip_runtime.h>

// LSTMAttentionCell: 3-layer LSTM + Gaussian-mixture location attention.
// Round 1: correctness-first full-fp32.
//   - pack concatenated inputs X and weights Wc=[W_ih|W_hh] into ws (K padded
//     to a multiple of 16: 476->480, 876->880; pads are zero)
//   - gemm_nt: C[4096,1600] = X * Wc^T + bias  (64x64x16 LDS tile, fp32)
//   - gates_kernel: LSTM pointwise; writes h directly into the next packed X
//   - attn_kernel: one wave per row; W_attn staged in LDS
// ws usage: ~85.1 MB of floats.

#define B_SZ     4096
#define LSTM_N   400
#define NG       1600   // 4*LSTM
#define VOCAB    73
#define NATTN    10
#define CHARLEN  64
#define KP1      480    // padded 73+3+400
#define KP23     880    // padded 3+400+73+400

constexpr int BM = 64, BN = 64, BK = 16;

// ---------------------------------------------------------------- pack weights
// Wc[n, 0:inw)      = W_ih[n, :]
// Wc[n, inw:inw+400)= W_hh[n, :]
// Wc[n, rest)       = 0
__global__ __launch_bounds__(256) void pack_w(const float* __restrict__ Wih, int inw,
                                              const float* __restrict__ Whh,
                                              float* __restrict__ Wc, int Kp)
{
    int n = blockIdx.y;
    int k = blockIdx.x * 256 + threadIdx.x;
    if (k >= Kp) return;
    float v = 0.f;
    if (k < inw)            v = Wih[(size_t)n * inw + k];
    else if (k < inw + 400) v = Whh[(size_t)n * 400 + (k - inw)];
    Wc[(size_t)n * Kp + k] = v;
}

// ---------------------------------------------------------------- pack X1 / XA
// X1 = [w_prev(73) | inputs(3) | h1(400) | 0pad]
// XA = [w_prev(73) | inputs(3) | (h1n written later by gates1) | 0pad]
__global__ __launch_bounds__(256) void pack_x1(const float* __restrict__ w_prev,
                                               const float* __restrict__ inputs,
                                               const float* __restrict__ h1,
                                               float* __restrict__ X1,
                                               float* __restrict__ XA)
{
    int b = blockIdx.y;
    int k = blockIdx.x * 256 + threadIdx.x;
    if (k >= KP1) return;
    float v = 0.f;
    if (k < 73)        v = w_prev[(size_t)b * 73 + k];
    else if (k < 76)   v = inputs[(size_t)b * 3 + (k - 73)];
    else if (k < 476)  v = h1[(size_t)b * 400 + (k - 76)];
    X1[(size_t)b * KP1 + k] = v;
    if (k < 76 || k >= 476) XA[(size_t)b * KP1 + k] = v;  // h region filled by gates1
}

// ---------------------------------------------------------------- pack X2 / X3
// X2 = [inputs(3) | h1n(gates1) | w(attn) | h2(400) | 0pad]
// X3 = [inputs(3) | h2n(gates2) | w(attn) | h3(400) | 0pad]
__global__ __launch_bounds__(256) void pack_x23(const float* __restrict__ inputs,
                                                const float* __restrict__ h2,
                                                const float* __restrict__ h3,
                                                float* __restrict__ X2,
                                                float* __restrict__ X3)
{
    int b = blockIdx.y;
    int k = blockIdx.x * 256 + threadIdx.x;
    if (k >= KP23) return;
    if (k >= 3 && k < 476) return;  // filled by gates1/gates2/attn
    float v2 = 0.f, v3 = 0.f;
    if (k < 3) { v2 = inputs[(size_t)b * 3 + k]; v3 = v2; }
    else if (k >= 476 && k < 876) {
        v2 = h2[(size_t)b * 400 + (k - 476)];
        v3 = h3[(size_t)b * 400 + (k - 476)];
    }
    X2[(size_t)b * KP23 + k] = v2;
    X3[(size_t)b * KP23 + k] = v3;
}

// ---------------------------------------------------------------- fp32 NT GEMM
// C[m,n] = sum_k A[m,k]*Bw[n,k] + bias[n];  M=4096, N=1600, K=Kp (mult of 16)
__global__ __launch_bounds__(256) void gemm_nt(const float* __restrict__ A,
                                               const float* __restrict__ Bw,
                                               const float* __restrict__ bias,
                                               float* __restrict__ C, int Kp)
{
    __shared__ float As[BK][BM + 4];
    __shared__ float Bs[BK][BN + 4];
    const int t  = threadIdx.x;
    const int m0 = blockIdx.y * BM;
    const int n0 = blockIdx.x * BN;
    const int lm = t >> 2;          // 0..63
    const int lk = (t & 3) << 2;    // 0,4,8,12
    const int ti = t >> 4;          // 0..15
    const int tj = t & 15;          // 0..15
    float acc[4][4] = {};

    for (int k0 = 0; k0 < Kp; k0 += BK) {
        float4 av = *(const float4*)(A  + (size_t)(m0 + lm) * Kp + k0 + lk);
        float4 bv = *(const float4*)(Bw + (size_t)(n0 + lm) * Kp + k0 + lk);
        As[lk + 0][lm] = av.x; As[lk + 1][lm] = av.y;
        As[lk + 2][lm] = av.z; As[lk + 3][lm] = av.w;
        Bs[lk + 0][lm] = bv.x; Bs[lk + 1][lm] = bv.y;
        Bs[lk + 2][lm] = bv.z; Bs[lk + 3][lm] = bv.w;
        __syncthreads();
#pragma unroll
        for (int kk = 0; kk < BK; kk++) {
            float4 a4 = *(const float4*)(&As[kk][4 * ti]);
            float4 b4 = *(const float4*)(&Bs[kk][4 * tj]);
            acc[0][0] += a4.x * b4.x; acc[0][1] += a4.x * b4.y;
            acc[0][2] += a4.x * b4.z; acc[0][3] += a4.x * b4.w;
            acc[1][0] += a4.y * b4.x; acc[1][1] += a4.y * b4.y;
            acc[1][2] += a4.y * b4.z; acc[1][3] += a4.y * b4.w;
            acc[2][0] += a4.z * b4.x; acc[2][1] += a4.z * b4.y;
            acc[2][2] += a4.z * b4.z; acc[2][3] += a4.z * b4.w;
            acc[3][0] += a4.w * b4.x; acc[3][1] += a4.w * b4.y;
            acc[3][2] += a4.w * b4.z; acc[3][3] += a4.w * b4.w;
        }
        __syncthreads();
    }

    float4 bb = *(const float4*)(bias + n0 + 4 * tj);
#pragma unroll
    for (int a = 0; a < 4; a++) {
        float4 o;
        o.x = acc[a][0] + bb.x; o.y = acc[a][1] + bb.y;
        o.z = acc[a][2] + bb.z; o.w = acc[a][3] + bb.w;
        *(float4*)(C + (size_t)(m0 + 4 * ti + a) * NG + n0 + 4 * tj) = o;
    }
}

// ---------------------------------------------------------------- LSTM gates
// G: [B, 1600] pre-activation (i,f,g,o).  h -> d1[b*ld1+u] (+ optional d2).
__global__ __launch_bounds__(256) void gates_kernel(const float* __restrict__ G,
                                                    const float* __restrict__ c_in,
                                                    float* __restrict__ d1, int ld1,
                                                    float* __restrict__ d2, int ld2)
{
    int id = blockIdx.x * 256 + threadIdx.x;
    if (id >= B_SZ * LSTM_N) return;
    int b = id / LSTM_N;
    int u = id - b * LSTM_N;
    const float* g = G + (size_t)b * NG;
    float gi = g[u];
    float gf = g[LSTM_N + u];
    float gc = g[2 * LSTM_N + u];
    float go = g[3 * LSTM_N + u];
    float si = 1.f / (1.f + __expf(-gi));
    float sf = 1.f / (1.f + __expf(-gf));
    float so = 1.f / (1.f + __expf(-go));
    float cn = sf * c_in[id] + si * tanhf(gc);
    float h  = so * tanhf(cn);
    d1[(size_t)b * ld1 + u] = h;
    if (d2) d2[(size_t)b * ld2 + u] = h;
}

// ---------------------------------------------------------------- attention
// One wave (64 lanes) per batch row; 4 rows per 256-thread block.
// XA row (lda KP1) -> 30 softplus params -> phi[64] -> w[73] into X2,X3 col 403.
#define AROWS 4
__global__ __launch_bounds__(256) void attn_kernel(const float* __restrict__ XA,
                                                   const float* __restrict__ W_attn,
                                                   const float* __restrict__ b_attn,
                                                   const float* __restrict__ kappa,
                                                   const float* __restrict__ AV,
                                                   const int* __restrict__ alen,
                                                   float* __restrict__ X2,
                                                   float* __restrict__ X3)
{
    __shared__ float Ws[30 * 476];
    __shared__ float bs[30];
    __shared__ float prm[AROWS][32];     // 0-9 alpha, 10-19 beta, 20-29 kappa
    __shared__ float phi_s[AROWS][CHARLEN];

    const int t = threadIdx.x;
    for (int i = t; i < 30 * 476; i += 256) Ws[i] = W_attn[i];
    if (t < 30) bs[t] = b_attn[t];
    __syncthreads();

    const int wave = t >> 6;
    const int lane = t & 63;
    const int b = blockIdx.x * AROWS + wave;

    // phase 1: 30 dot products of length 476
    float acc[30];
#pragma unroll
    for (int j = 0; j < 30; j++) acc[j] = 0.f;
    const float* xrow = XA + (size_t)b * KP1;
    for (int k = lane; k < 476; k += 64) {
        float x = xrow[k];
#pragma unroll
        for (int j = 0; j < 30; j++) acc[j] += x * Ws[j * 476 + k];
    }
#pragma unroll
    for (int j = 0; j < 30; j++) {
        float v = acc[j];
        for (int s = 32; s > 0; s >>= 1) v += __shfl_xor(v, s, 64);
        if (lane == 0) {
            float p  = v + bs[j];
            float sp = (p > 20.f) ? p : log1pf(__expf(p));
            if (j < 10)       prm[wave][j] = sp;                       // alpha
            else if (j < 20)  prm[wave][j] = fmaxf(sp, 0.01f);         // beta
            else              prm[wave][j] = kappa[(size_t)b * NATTN + (j - 20)] + sp * (1.f / 25.f);
        }
    }
    __syncthreads();

    // phase 2: phi over 64 char positions (lane == position)
    {
        int c = lane;
        float phi = 0.f;
#pragma unroll
        for (int j = 0; j < NATTN; j++) {
            float d = prm[wave][20 + j] - (float)c;
            phi += prm[wave][j] * __expf(-d * d / prm[wave][10 + j]);
        }
        int len = alen[b];
        phi_s[wave][c] = (c < len) ? phi : 0.f;
    }
    __syncthreads();

    // phase 3: w[v] = sum_c phi[c] * AV[b,c,v]
    for (int v = lane; v < VOCAB; v += 64) {
        float s = 0.f;
        const float* avb = AV + (size_t)b * CHARLEN * VOCAB + v;
#pragma unroll
        for (int c = 0; c < CHARLEN; c++) s += phi_s[wave][c] * avb[(size_t)c * VOCAB];
        X2[(size_t)b * KP23 + 403 + v] = s;
        X3[(size_t)b * KP23 + 403 + v] = s;
    }
}

// ---------------------------------------------------------------- launch
extern "C" void kernel_launch(void* const* d_in, const int* in_sizes, int n_in,
                              void* d_out, int out_size, void* d_ws, size_t ws_size,
                              hipStream_t stream)
{
    const float* inputs = (const float*)d_in[0];
    const float* h1     = (const float*)d_in[1];
    const float* c1     = (const float*)d_in[2];
    const float* h2     = (const float*)d_in[3];
    const float* c2     = (const float*)d_in[4];
    const float* h3     = (const float*)d_in[5];
    const float* c3     = (const float*)d_in[6];
    const float* kappa  = (const float*)d_in[7];
    const float* w_prev = (const float*)d_in[8];
    const float* AV     = (const float*)d_in[9];
    const int*   alen   = (const int*)d_in[10];
    const float* W_ih1  = (const float*)d_in[11];
    const float* W_hh1  = (const float*)d_in[12];
    const float* b1     = (const float*)d_in[13];
    const float* W_attn = (const float*)d_in[14];
    const float* b_attn = (const float*)d_in[15];
    const float* W_ih2  = (const float*)d_in[16];
    const float* W_hh2  = (const float*)d_in[17];
    const float* b2     = (const float*)d_in[18];
    const float* W_ih3  = (const float*)d_in[19];
    const float* W_hh3  = (const float*)d_in[20];
    const float* b3     = (const float*)d_in[21];
    float* out = (float*)d_out;
    float* ws  = (float*)d_ws;

    float* X1  = ws;
    float* XA  = X1  + (size_t)B_SZ * KP1;
    float* X2  = XA  + (size_t)B_SZ * KP1;
    float* X3  = X2  + (size_t)B_SZ * KP23;
    float* Wc1 = X3  + (size_t)B_SZ * KP23;
    float* Wc2 = Wc1 + (size_t)NG * KP1;
    float* Wc3 = Wc2 + (size_t)NG * KP23;
    float* G   = Wc3 + (size_t)NG * KP23;

    pack_w<<<dim3(2, NG), 256, 0, stream>>>(W_ih1, 76,  W_hh1, Wc1, KP1);
    pack_w<<<dim3(4, NG), 256, 0, stream>>>(W_ih2, 476, W_hh2, Wc2, KP23);
    pack_w<<<dim3(4, NG), 256, 0, stream>>>(W_ih3, 476, W_hh3, Wc3, KP23);
    pack_x1<<<dim3(2, B_SZ), 256, 0, stream>>>(w_prev, inputs, h1, X1, XA);
    pack_x23<<<dim3(4, B_SZ), 256, 0, stream>>>(inputs, h2, h3, X2, X3);

    const int gates_blocks = (B_SZ * LSTM_N + 255) / 256;

    // LSTM1
    gemm_nt<<<dim3(25, 64), 256, 0, stream>>>(X1, Wc1, b1, G, KP1);
    gates_kernel<<<gates_blocks, 256, 0, stream>>>(G, c1, XA + 76, KP1, X2 + 3, KP23);
    // attention (needs h1n in XA)
    attn_kernel<<<B_SZ / AROWS, 256, 0, stream>>>(XA, W_attn, b_attn, kappa, AV, alen, X2, X3);
    // LSTM2
    gemm_nt<<<dim3(25, 64), 256, 0, stream>>>(X2, Wc2, b2, G, KP23);
    gates_kernel<<<gates_blocks, 256, 0, stream>>>(G, c2, X3 + 3, KP23, nullptr, 0);
    // LSTM3
    gemm_nt<<<dim3(25, 64), 256, 0, stream>>>(X3, Wc3, b3, G, KP23);
    gates_kernel<<<gates_blocks, 256, 0, stream>>>(G, c3, out, LSTM_N, nullptr, 0);
}

// Round 3
// 449.039 us; speedup vs baseline: 1.7602x; 1.7602x over previous
//
#include <hip/hip_runtime.h>
#include <hip/hip_bf16.h>

// Round 3: split-bf16 (hi/lo) MFMA GEMMs -> fp32-level accuracy on matrix pipe.
// A = Ah + Al, B = Bh + Bl (bf16 each); C += Ah*Bh + Al*Bh + Ah*Bl.
// Attention reads exact fp32 inputs (w_prev/inputs direct, h1n from fp32 buf).

#define B_SZ     4096
#define LSTM_N   400
#define NG       1600   // 4*LSTM
#define NGP      1664   // padded to 13*128
#define VOCAB    73
#define NATTN    10
#define CHARLEN  64
#define KP1      480    // padded 73+3+400  (mult of 32)
#define KP23     896    // padded 3+400+73+400 (mult of 32)

typedef __attribute__((ext_vector_type(8))) short short8;
typedef __attribute__((ext_vector_type(4))) float floatx4;

__device__ __forceinline__ void gload_lds16(const void* g, void* l) {
    __builtin_amdgcn_global_load_lds(
        (const __attribute__((address_space(1))) void*)g,
        (__attribute__((address_space(3))) void*)l, 16, 0, 0);
}

__device__ __forceinline__ void split_bf16(float v, __hip_bfloat16* hi, __hip_bfloat16* lo) {
    __hip_bfloat16 h = __float2bfloat16(v);
    *hi = h;
    *lo = __float2bfloat16(v - __bfloat162float(h));
}

// ---------------------------------------------------------------- pack weights
__global__ __launch_bounds__(256) void pack_w(const float* __restrict__ Wih, int inw,
                                              const float* __restrict__ Whh,
                                              __hip_bfloat16* __restrict__ Wh,
                                              __hip_bfloat16* __restrict__ Wl, int Kp)
{
    int n = blockIdx.y;
    int k = blockIdx.x * 256 + threadIdx.x;
    if (k >= Kp) return;
    float v = 0.f;
    if (n < NG) {
        if (k < inw)            v = Wih[(size_t)n * inw + k];
        else if (k < inw + 400) v = Whh[(size_t)n * 400 + (k - inw)];
    }
    __hip_bfloat16 hi, lo;
    split_bf16(v, &hi, &lo);
    Wh[(size_t)n * Kp + k] = hi;
    Wl[(size_t)n * Kp + k] = lo;
}

// ---------------------------------------------------------------- pack X1
// X1 = [w_prev(73) | inputs(3) | h1(400) | 0pad]
__global__ __launch_bounds__(256) void pack_x1(const float* __restrict__ w_prev,
                                               const float* __restrict__ inputs,
                                               const float* __restrict__ h1,
                                               __hip_bfloat16* __restrict__ Xh,
                                               __hip_bfloat16* __restrict__ Xl)
{
    int b = blockIdx.y;
    int k = blockIdx.x * 256 + threadIdx.x;
    if (k >= KP1) return;
    float v = 0.f;
    if (k < 73)        v = w_prev[(size_t)b * 73 + k];
    else if (k < 76)   v = inputs[(size_t)b * 3 + (k - 73)];
    else if (k < 476)  v = h1[(size_t)b * 400 + (k - 76)];
    __hip_bfloat16 hi, lo;
    split_bf16(v, &hi, &lo);
    Xh[(size_t)b * KP1 + k] = hi;
    Xl[(size_t)b * KP1 + k] = lo;
}

// ---------------------------------------------------------------- pack X2 / X3
// X2 = [inputs(3) | h1n(g1) | w(attn) | h2(400) | 0pad]
// X3 = [inputs(3) | h2n(g2) | w(attn) | h3(400) | 0pad]
__global__ __launch_bounds__(256) void pack_x23(const float* __restrict__ inputs,
                                                const float* __restrict__ h2,
                                                const float* __restrict__ h3,
                                                __hip_bfloat16* __restrict__ X2h,
                                                __hip_bfloat16* __restrict__ X2l,
                                                __hip_bfloat16* __restrict__ X3h,
                                                __hip_bfloat16* __restrict__ X3l)
{
    int b = blockIdx.y;
    int k = blockIdx.x * 256 + threadIdx.x;
    if (k >= KP23) return;
    if (k >= 3 && k < 476) return;  // h by gates1/2, w by attn
    float v2 = 0.f, v3 = 0.f;
    if (k < 3) { v2 = inputs[(size_t)b * 3 + k]; v3 = v2; }
    else if (k >= 476 && k < 876) {
        v2 = h2[(size_t)b * 400 + (k - 476)];
        v3 = h3[(size_t)b * 400 + (k - 476)];
    }
    __hip_bfloat16 hi, lo;
    split_bf16(v2, &hi, &lo);
    X2h[(size_t)b * KP23 + k] = hi;
    X2l[(size_t)b * KP23 + k] = lo;
    split_bf16(v3, &hi, &lo);
    X3h[(size_t)b * KP23 + k] = hi;
    X3l[(size_t)b * KP23 + k] = lo;
}

// ---------------------------------------------------------------- split GEMM
// C[m,n] = sum_k A[m,k]*Bw[n,k] + bias[n];  A=Ah+Al, Bw=Bh+Bl.
// M=4096, N=NGP computed / NG stored (ld NG), K=Kp (mult 32).
__global__ __launch_bounds__(256) void gemm_split(const short* __restrict__ Ah,
                                                  const short* __restrict__ Al,
                                                  const short* __restrict__ Bh,
                                                  const short* __restrict__ Bl,
                                                  const float* __restrict__ bias,
                                                  float* __restrict__ C, int Kp)
{
    __shared__ short AsH[128 * 32];
    __shared__ short AsL[128 * 32];
    __shared__ short BsH[128 * 32];
    __shared__ short BsL[128 * 32];

    const int t    = threadIdx.x;
    const int w    = t >> 6;
    const int lane = t & 63;
    const int quad = lane >> 4;
    const int l16  = lane & 15;
    const int m0   = blockIdx.y * 128;
    const int n0   = blockIdx.x * 128;
    const int wm   = (w >> 1) * 64;
    const int wn   = (w & 1) * 64;
    const int ldrow = lane >> 2;        // 0..15
    const int lseg  = (lane & 3) * 8;   // k offset (16B)

    floatx4 acc[4][4] = {};

    for (int k0 = 0; k0 < Kp; k0 += 32) {
        __syncthreads();
#pragma unroll
        for (int j = 0; j < 2; j++) {
            const int cr = (j * 4 + w) * 16;   // wave-uniform chunk row
            const size_t goA = (size_t)(m0 + cr + ldrow) * Kp + k0 + lseg;
            const size_t goB = (size_t)(n0 + cr + ldrow) * Kp + k0 + lseg;
            gload_lds16(Ah + goA, AsH + cr * 32);
            gload_lds16(Al + goA, AsL + cr * 32);
            gload_lds16(Bh + goB, BsH + cr * 32);
            gload_lds16(Bl + goB, BsL + cr * 32);
        }
        asm volatile("s_waitcnt vmcnt(0)" ::: "memory");
        __syncthreads();

        short8 afh[4], afl[4], bfh[4], bfl[4];
#pragma unroll
        for (int i = 0; i < 4; i++) {
            afh[i] = *(const short8*)(AsH + (wm + i * 16 + l16) * 32 + quad * 8);
            afl[i] = *(const short8*)(AsL + (wm + i * 16 + l16) * 32 + quad * 8);
            bfh[i] = *(const short8*)(BsH + (wn + i * 16 + l16) * 32 + quad * 8);
            bfl[i] = *(const short8*)(BsL + (wn + i * 16 + l16) * 32 + quad * 8);
        }
#pragma unroll
        for (int mt = 0; mt < 4; mt++)
#pragma unroll
            for (int nt = 0; nt < 4; nt++) {
                acc[mt][nt] = __builtin_amdgcn_mfma_f32_16x16x32_bf16(
                    afh[mt], bfh[nt], acc[mt][nt], 0, 0, 0);
                acc[mt][nt] = __builtin_amdgcn_mfma_f32_16x16x32_bf16(
                    afl[mt], bfh[nt], acc[mt][nt], 0, 0, 0);
                acc[mt][nt] = __builtin_amdgcn_mfma_f32_16x16x32_bf16(
                    afh[mt], bfl[nt], acc[mt][nt], 0, 0, 0);
            }
    }

#pragma unroll
    for (int nt = 0; nt < 4; nt++) {
        const int n = n0 + wn + nt * 16 + l16;
        if (n >= NG) continue;
        const float bv = bias[n];
#pragma unroll
        for (int mt = 0; mt < 4; mt++) {
            const int mbase = m0 + wm + mt * 16 + quad * 4;
#pragma unroll
            for (int r = 0; r < 4; r++)
                C[(size_t)(mbase + r) * NG + n] = acc[mt][nt][r] + bv;
        }
    }
}

// ---------------------------------------------------------------- LSTM gates
// h -> optional fp32 buf + optional bf16 hi/lo destination (ld elements)
__global__ __launch_bounds__(256) void gates_mid(const float* __restrict__ G,
                                                 const float* __restrict__ c_in,
                                                 float* __restrict__ Hf,
                                                 __hip_bfloat16* __restrict__ dh,
                                                 __hip_bfloat16* __restrict__ dl, int ld)
{
    int id = blockIdx.x * 256 + threadIdx.x;
    if (id >= B_SZ * LSTM_N) return;
    int b = id / LSTM_N;
    int u = id - b * LSTM_N;
    const float* g = G + (size_t)b * NG;
    float gi = g[u], gf = g[LSTM_N + u], gc = g[2 * LSTM_N + u], go = g[3 * LSTM_N + u];
    float si = 1.f / (1.f + expf(-gi));
    float sf = 1.f / (1.f + expf(-gf));
    float so = 1.f / (1.f + expf(-go));
    float cn = sf * c_in[id] + si * tanhf(gc);
    float h  = so * tanhf(cn);
    if (Hf) Hf[id] = h;
    __hip_bfloat16 hi, lo;
    split_bf16(h, &hi, &lo);
    dh[(size_t)b * ld + u] = hi;
    dl[(size_t)b * ld + u] = lo;
}

__global__ __launch_bounds__(256) void gates_last(const float* __restrict__ G,
                                                  const float* __restrict__ c_in,
                                                  float* __restrict__ out)
{
    int id = blockIdx.x * 256 + threadIdx.x;
    if (id >= B_SZ * LSTM_N) return;
    int b = id / LSTM_N;
    int u = id - b * LSTM_N;
    const float* g = G + (size_t)b * NG;
    float gi = g[u], gf = g[LSTM_N + u], gc = g[2 * LSTM_N + u], go = g[3 * LSTM_N + u];
    float si = 1.f / (1.f + expf(-gi));
    float sf = 1.f / (1.f + expf(-gf));
    float so = 1.f / (1.f + expf(-go));
    float cn = sf * c_in[id] + si * tanhf(gc);
    out[id]  = so * tanhf(cn);
}

// ---------------------------------------------------------------- attention
// 4 waves/block, ATTN_RPW rows/wave. Exact fp32 inputs.
#define ATTN_RPW 4
__global__ __launch_bounds__(256) void attn_kernel(const float* __restrict__ w_prev,
                                                   const float* __restrict__ inputs,
                                                   const float* __restrict__ H1,
                                                   const float* __restrict__ W_attn,
                                                   const float* __restrict__ b_attn,
                                                   const float* __restrict__ kappa,
                                                   const float* __restrict__ AV,
                                                   const int* __restrict__ alen,
                                                   __hip_bfloat16* __restrict__ X2h,
                                                   __hip_bfloat16* __restrict__ X2l,
                                                   __hip_bfloat16* __restrict__ X3h,
                                                   __hip_bfloat16* __restrict__ X3l)
{
    __shared__ float Ws[30 * 476];
    __shared__ float bs[30];
    __shared__ float prm[4][32];        // 0-9 alpha, 10-19 beta, 20-29 kappa
    __shared__ float phi_s[4][CHARLEN];

    const int t = threadIdx.x;
    for (int i = t; i < 30 * 476; i += 256) Ws[i] = W_attn[i];
    if (t < 30) bs[t] = b_attn[t];
    __syncthreads();

    const int wave = t >> 6;
    const int lane = t & 63;

    for (int r = 0; r < ATTN_RPW; r++) {
        const int b = blockIdx.x * (4 * ATTN_RPW) + wave * ATTN_RPW + r;

        // phase 1: 30 dot products of length 476 (exact fp32 inputs)
        float acc[30];
#pragma unroll
        for (int j = 0; j < 30; j++) acc[j] = 0.f;
        for (int k = lane; k < 476; k += 64) {
            float x;
            if (k < 73)      x = w_prev[(size_t)b * 73 + k];
            else if (k < 76) x = inputs[(size_t)b * 3 + (k - 73)];
            else             x = H1[(size_t)b * 400 + (k - 76)];
#pragma unroll
            for (int j = 0; j < 30; j++) acc[j] += x * Ws[j * 476 + k];
        }
#pragma unroll
        for (int j = 0; j < 30; j++) {
            float v = acc[j];
            for (int s = 32; s > 0; s >>= 1) v += __shfl_xor(v, s, 64);
            if (lane == 0) {
                float p  = v + bs[j];
                float sp = (p > 20.f) ? p : log1pf(expf(p));
                if (j < 10)       prm[wave][j] = sp;
                else if (j < 20)  prm[wave][j] = fmaxf(sp, 0.01f);
                else              prm[wave][j] = kappa[(size_t)b * NATTN + (j - 20)] + sp * (1.f / 25.f);
            }
        }
        __syncthreads();

        // phase 2: phi at char position = lane
        {
            int c = lane;
            float phi = 0.f;
#pragma unroll
            for (int j = 0; j < NATTN; j++) {
                float d = prm[wave][20 + j] - (float)c;
                phi += prm[wave][j] * expf(-d * d / prm[wave][10 + j]);
            }
            phi_s[wave][c] = (c < alen[b]) ? phi : 0.f;
        }
        __syncthreads();

        // phase 3: w[v] = sum_c phi[c] * AV[b,c,v]  -> hi/lo into X2,X3
        for (int v = lane; v < VOCAB; v += 64) {
            float s = 0.f;
            const float* avb = AV + (size_t)b * CHARLEN * VOCAB + v;
#pragma unroll
            for (int c = 0; c < CHARLEN; c++) s += phi_s[wave][c] * avb[(size_t)c * VOCAB];
            __hip_bfloat16 hi, lo;
            split_bf16(s, &hi, &lo);
            X2h[(size_t)b * KP23 + 403 + v] = hi;
            X2l[(size_t)b * KP23 + 403 + v] = lo;
            X3h[(size_t)b * KP23 + 403 + v] = hi;
            X3l[(size_t)b * KP23 + 403 + v] = lo;
        }
        __syncthreads();
    }
}

// ---------------------------------------------------------------- launch
extern "C" void kernel_launch(void* const* d_in, const int* in_sizes, int n_in,
                              void* d_out, int out_size, void* d_ws, size_t ws_size,
                              hipStream_t stream)
{
    const float* inputs = (const float*)d_in[0];
    const float* h1     = (const float*)d_in[1];
    const float* c1     = (const float*)d_in[2];
    const float* h2     = (const float*)d_in[3];
    const float* c2     = (const float*)d_in[4];
    const float* h3     = (const float*)d_in[5];
    const float* c3     = (const float*)d_in[6];
    const float* kappa  = (const float*)d_in[7];
    const float* w_prev = (const float*)d_in[8];
    const float* AV     = (const float*)d_in[9];
    const int*   alen   = (const int*)d_in[10];
    const float* W_ih1  = (const float*)d_in[11];
    const float* W_hh1  = (const float*)d_in[12];
    const float* b1     = (const float*)d_in[13];
    const float* W_attn = (const float*)d_in[14];
    const float* b_attn = (const float*)d_in[15];
    const float* W_ih2  = (const float*)d_in[16];
    const float* W_hh2  = (const float*)d_in[17];
    const float* b2     = (const float*)d_in[18];
    const float* W_ih3  = (const float*)d_in[19];
    const float* W_hh3  = (const float*)d_in[20];
    const float* b3     = (const float*)d_in[21];
    float* out = (float*)d_out;

    char* p = (char*)d_ws;
    __hip_bfloat16* X1h = (__hip_bfloat16*)p; p += (size_t)B_SZ * KP1 * 2;
    __hip_bfloat16* X1l = (__hip_bfloat16*)p; p += (size_t)B_SZ * KP1 * 2;
    __hip_bfloat16* X2h = (__hip_bfloat16*)p; p += (size_t)B_SZ * KP23 * 2;
    __hip_bfloat16* X2l = (__hip_bfloat16*)p; p += (size_t)B_SZ * KP23 * 2;
    __hip_bfloat16* X3h = (__hip_bfloat16*)p; p += (size_t)B_SZ * KP23 * 2;
    __hip_bfloat16* X3l = (__hip_bfloat16*)p; p += (size_t)B_SZ * KP23 * 2;
    __hip_bfloat16* W1h = (__hip_bfloat16*)p; p += (size_t)NGP * KP1 * 2;
    __hip_bfloat16* W1l = (__hip_bfloat16*)p; p += (size_t)NGP * KP1 * 2;
    __hip_bfloat16* W2h = (__hip_bfloat16*)p; p += (size_t)NGP * KP23 * 2;
    __hip_bfloat16* W2l = (__hip_bfloat16*)p; p += (size_t)NGP * KP23 * 2;
    __hip_bfloat16* W3h = (__hip_bfloat16*)p; p += (size_t)NGP * KP23 * 2;
    __hip_bfloat16* W3l = (__hip_bfloat16*)p; p += (size_t)NGP * KP23 * 2;
    float* H1 = (float*)p;  p += (size_t)B_SZ * LSTM_N * 4;
    float* G  = (float*)p;  // B_SZ * NG * 4 = 26.2 MB  (total ~85.1 MB)

    pack_w<<<dim3(2, NGP), 256, 0, stream>>>(W_ih1, 76,  W_hh1, W1h, W1l, KP1);
    pack_w<<<dim3(4, NGP), 256, 0, stream>>>(W_ih2, 476, W_hh2, W2h, W2l, KP23);
    pack_w<<<dim3(4, NGP), 256, 0, stream>>>(W_ih3, 476, W_hh3, W3h, W3l, KP23);
    pack_x1<<<dim3(2, B_SZ), 256, 0, stream>>>(w_prev, inputs, h1, X1h, X1l);
    pack_x23<<<dim3(4, B_SZ), 256, 0, stream>>>(inputs, h2, h3, X2h, X2l, X3h, X3l);

    const int gates_blocks = (B_SZ * LSTM_N + 255) / 256;
    const dim3 gemm_grid(NGP / 128, B_SZ / 128);

    // LSTM1
    gemm_split<<<gemm_grid, 256, 0, stream>>>((const short*)X1h, (const short*)X1l,
                                              (const short*)W1h, (const short*)W1l, b1, G, KP1);
    gates_mid<<<gates_blocks, 256, 0, stream>>>(G, c1, H1, X2h + 3, X2l + 3, KP23);
    // attention (needs h1n)
    attn_kernel<<<B_SZ / 16, 256, 0, stream>>>(w_prev, inputs, H1, W_attn, b_attn,
                                               kappa, AV, alen, X2h, X2l, X3h, X3l);
    // LSTM2
    gemm_split<<<gemm_grid, 256, 0, stream>>>((const short*)X2h, (const short*)X2l,
                                              (const short*)W2h, (const short*)W2l, b2, G, KP23);
    gates_mid<<<gates_blocks, 256, 0, stream>>>(G, c2, nullptr, X3h + 3, X3l + 3, KP23);
    // LSTM3
    gemm_split<<<gemm_grid, 256, 0, stream>>>((const short*)X3h, (const short*)X3l,
                                              (const short*)W3h, (const short*)W3l, b3, G, KP23);
    gates_last<<<gates_blocks, 256, 0, stream>>>(G, c3, out);
}

// Round 4
// 401.418 us; speedup vs baseline: 1.9690x; 1.1186x over previous
//
#include <hip/hip_runtime.h>
#include <hip/hip_bf16.h>

// Round 4: split-bf16 MFMA GEMMs + attention restructured:
//   - attention param projection folded into an MFMA GEMM (X1 is reused:
//     gates1 overwrites its h-region with h1n -> X1 == [w_prev|inputs|h1n])
//   - attn_phi: wave-per-row phi+einsum, c-loop bounded by alen[b]

#define B_SZ     4096
#define LSTM_N   400
#define NG       1600   // 4*LSTM
#define NGP      1664   // padded to 13*128
#define VOCAB    73
#define NATTN    10
#define CHARLEN  64
#define KP1      480    // padded 73+3+400  (mult of 32)
#define KP23     896    // padded 3+400+73+400 (mult of 32)

typedef __attribute__((ext_vector_type(8))) short short8;
typedef __attribute__((ext_vector_type(4))) float floatx4;

__device__ __forceinline__ void gload_lds16(const void* g, void* l) {
    __builtin_amdgcn_global_load_lds(
        (const __attribute__((address_space(1))) void*)g,
        (__attribute__((address_space(3))) void*)l, 16, 0, 0);
}

__device__ __forceinline__ void split_bf16(float v, __hip_bfloat16* hi, __hip_bfloat16* lo) {
    __hip_bfloat16 h = __float2bfloat16(v);
    *hi = h;
    *lo = __float2bfloat16(v - __bfloat162float(h));
}

// ---------------------------------------------------------------- pack weights
__global__ __launch_bounds__(256) void pack_w(const float* __restrict__ Wih, int inw,
                                              const float* __restrict__ Whh,
                                              __hip_bfloat16* __restrict__ Wh,
                                              __hip_bfloat16* __restrict__ Wl, int Kp)
{
    int n = blockIdx.y;
    int k = blockIdx.x * 256 + threadIdx.x;
    if (k >= Kp) return;
    float v = 0.f;
    if (n < NG) {
        if (k < inw)            v = Wih[(size_t)n * inw + k];
        else if (k < inw + 400) v = Whh[(size_t)n * 400 + (k - inw)];
    }
    __hip_bfloat16 hi, lo;
    split_bf16(v, &hi, &lo);
    Wh[(size_t)n * Kp + k] = hi;
    Wl[(size_t)n * Kp + k] = lo;
}

// pack W_attn [30,476] into 128x480 hi/lo (rows>=30 and cols>=476 are zero)
__global__ __launch_bounds__(256) void pack_wa(const float* __restrict__ W_attn,
                                               __hip_bfloat16* __restrict__ Wh,
                                               __hip_bfloat16* __restrict__ Wl)
{
    int n = blockIdx.y;
    int k = blockIdx.x * 256 + threadIdx.x;
    if (k >= KP1) return;
    float v = (n < 30 && k < 476) ? W_attn[(size_t)n * 476 + k] : 0.f;
    __hip_bfloat16 hi, lo;
    split_bf16(v, &hi, &lo);
    Wh[(size_t)n * KP1 + k] = hi;
    Wl[(size_t)n * KP1 + k] = lo;
}

// ---------------------------------------------------------------- pack X1
// X1 = [w_prev(73) | inputs(3) | h1(400) | 0pad]; h-region replaced by h1n later
__global__ __launch_bounds__(256) void pack_x1(const float* __restrict__ w_prev,
                                               const float* __restrict__ inputs,
                                               const float* __restrict__ h1,
                                               __hip_bfloat16* __restrict__ Xh,
                                               __hip_bfloat16* __restrict__ Xl)
{
    int b = blockIdx.y;
    int k = blockIdx.x * 256 + threadIdx.x;
    if (k >= KP1) return;
    float v = 0.f;
    if (k < 73)        v = w_prev[(size_t)b * 73 + k];
    else if (k < 76)   v = inputs[(size_t)b * 3 + (k - 73)];
    else if (k < 476)  v = h1[(size_t)b * 400 + (k - 76)];
    __hip_bfloat16 hi, lo;
    split_bf16(v, &hi, &lo);
    Xh[(size_t)b * KP1 + k] = hi;
    Xl[(size_t)b * KP1 + k] = lo;
}

// ---------------------------------------------------------------- pack X2 / X3
__global__ __launch_bounds__(256) void pack_x23(const float* __restrict__ inputs,
                                                const float* __restrict__ h2,
                                                const float* __restrict__ h3,
                                                __hip_bfloat16* __restrict__ X2h,
                                                __hip_bfloat16* __restrict__ X2l,
                                                __hip_bfloat16* __restrict__ X3h,
                                                __hip_bfloat16* __restrict__ X3l)
{
    int b = blockIdx.y;
    int k = blockIdx.x * 256 + threadIdx.x;
    if (k >= KP23) return;
    if (k >= 3 && k < 476) return;  // h by gates1/2, w by attn
    float v2 = 0.f, v3 = 0.f;
    if (k < 3) { v2 = inputs[(size_t)b * 3 + k]; v3 = v2; }
    else if (k >= 476 && k < 876) {
        v2 = h2[(size_t)b * 400 + (k - 476)];
        v3 = h3[(size_t)b * 400 + (k - 476)];
    }
    __hip_bfloat16 hi, lo;
    split_bf16(v2, &hi, &lo);
    X2h[(size_t)b * KP23 + k] = hi;
    X2l[(size_t)b * KP23 + k] = lo;
    split_bf16(v3, &hi, &lo);
    X3h[(size_t)b * KP23 + k] = hi;
    X3l[(size_t)b * KP23 + k] = lo;
}

// ---------------------------------------------------------------- split GEMM
// C[m,n] = sum_k A[m,k]*Bw[n,k] + bias[n];  A=Ah+Al, Bw=Bh+Bl.
// Stores n < Nvalid with leading dim ldC.
__global__ __launch_bounds__(256) void gemm_split(const short* __restrict__ Ah,
                                                  const short* __restrict__ Al,
                                                  const short* __restrict__ Bh,
                                                  const short* __restrict__ Bl,
                                                  const float* __restrict__ bias,
                                                  float* __restrict__ C, int Kp,
                                                  int ldC, int Nvalid)
{
    __shared__ short AsH[128 * 32];
    __shared__ short AsL[128 * 32];
    __shared__ short BsH[128 * 32];
    __shared__ short BsL[128 * 32];

    const int t    = threadIdx.x;
    const int w    = t >> 6;
    const int lane = t & 63;
    const int quad = lane >> 4;
    const int l16  = lane & 15;
    const int m0   = blockIdx.y * 128;
    const int n0   = blockIdx.x * 128;
    const int wm   = (w >> 1) * 64;
    const int wn   = (w & 1) * 64;
    const int ldrow = lane >> 2;        // 0..15
    const int lseg  = (lane & 3) * 8;   // k offset (16B)

    floatx4 acc[4][4] = {};

    for (int k0 = 0; k0 < Kp; k0 += 32) {
        __syncthreads();
#pragma unroll
        for (int j = 0; j < 2; j++) {
            const int cr = (j * 4 + w) * 16;   // wave-uniform chunk row
            const size_t goA = (size_t)(m0 + cr + ldrow) * Kp + k0 + lseg;
            const size_t goB = (size_t)(n0 + cr + ldrow) * Kp + k0 + lseg;
            gload_lds16(Ah + goA, AsH + cr * 32);
            gload_lds16(Al + goA, AsL + cr * 32);
            gload_lds16(Bh + goB, BsH + cr * 32);
            gload_lds16(Bl + goB, BsL + cr * 32);
        }
        asm volatile("s_waitcnt vmcnt(0)" ::: "memory");
        __syncthreads();

        short8 afh[4], afl[4], bfh[4], bfl[4];
#pragma unroll
        for (int i = 0; i < 4; i++) {
            afh[i] = *(const short8*)(AsH + (wm + i * 16 + l16) * 32 + quad * 8);
            afl[i] = *(const short8*)(AsL + (wm + i * 16 + l16) * 32 + quad * 8);
            bfh[i] = *(const short8*)(BsH + (wn + i * 16 + l16) * 32 + quad * 8);
            bfl[i] = *(const short8*)(BsL + (wn + i * 16 + l16) * 32 + quad * 8);
        }
#pragma unroll
        for (int mt = 0; mt < 4; mt++)
#pragma unroll
            for (int nt = 0; nt < 4; nt++) {
                acc[mt][nt] = __builtin_amdgcn_mfma_f32_16x16x32_bf16(
                    afh[mt], bfh[nt], acc[mt][nt], 0, 0, 0);
                acc[mt][nt] = __builtin_amdgcn_mfma_f32_16x16x32_bf16(
                    afl[mt], bfh[nt], acc[mt][nt], 0, 0, 0);
                acc[mt][nt] = __builtin_amdgcn_mfma_f32_16x16x32_bf16(
                    afh[mt], bfl[nt], acc[mt][nt], 0, 0, 0);
            }
    }

#pragma unroll
    for (int nt = 0; nt < 4; nt++) {
        const int n = n0 + wn + nt * 16 + l16;
        if (n >= Nvalid) continue;
        const float bv = bias[n];
#pragma unroll
        for (int mt = 0; mt < 4; mt++) {
            const int mbase = m0 + wm + mt * 16 + quad * 4;
#pragma unroll
            for (int r = 0; r < 4; r++)
                C[(size_t)(mbase + r) * ldC + n] = acc[mt][nt][r] + bv;
        }
    }
}

// ---------------------------------------------------------------- LSTM gates
// h -> (dh1,dl1,ld1) and optionally (dh2,dl2,ld2)
__global__ __launch_bounds__(256) void gates_mid(const float* __restrict__ G,
                                                 const float* __restrict__ c_in,
                                                 __hip_bfloat16* __restrict__ dh1,
                                                 __hip_bfloat16* __restrict__ dl1, int ld1,
                                                 __hip_bfloat16* __restrict__ dh2,
                                                 __hip_bfloat16* __restrict__ dl2, int ld2)
{
    int id = blockIdx.x * 256 + threadIdx.x;
    if (id >= B_SZ * LSTM_N) return;
    int b = id / LSTM_N;
    int u = id - b * LSTM_N;
    const float* g = G + (size_t)b * NG;
    float gi = g[u], gf = g[LSTM_N + u], gc = g[2 * LSTM_N + u], go = g[3 * LSTM_N + u];
    float si = 1.f / (1.f + expf(-gi));
    float sf = 1.f / (1.f + expf(-gf));
    float so = 1.f / (1.f + expf(-go));
    float cn = sf * c_in[id] + si * tanhf(gc);
    float h  = so * tanhf(cn);
    __hip_bfloat16 hi, lo;
    split_bf16(h, &hi, &lo);
    dh1[(size_t)b * ld1 + u] = hi;
    dl1[(size_t)b * ld1 + u] = lo;
    if (dh2) {
        dh2[(size_t)b * ld2 + u] = hi;
        dl2[(size_t)b * ld2 + u] = lo;
    }
}

__global__ __launch_bounds__(256) void gates_last(const float* __restrict__ G,
                                                  const float* __restrict__ c_in,
                                                  float* __restrict__ out)
{
    int id = blockIdx.x * 256 + threadIdx.x;
    if (id >= B_SZ * LSTM_N) return;
    int b = id / LSTM_N;
    int u = id - b * LSTM_N;
    const float* g = G + (size_t)b * NG;
    float gi = g[u], gf = g[LSTM_N + u], gc = g[2 * LSTM_N + u], go = g[3 * LSTM_N + u];
    float si = 1.f / (1.f + expf(-gi));
    float sf = 1.f / (1.f + expf(-gf));
    float so = 1.f / (1.f + expf(-go));
    float cn = sf * c_in[id] + si * tanhf(gc);
    out[id]  = so * tanhf(cn);
}

// ---------------------------------------------------------------- attn phi+w
// wave = one batch row; 4 waves/block; grid B/4.
// AP[b,0:30] = preacts (softplus pending). phi over 64 chars; einsum vs AV.
__global__ __launch_bounds__(256) void attn_phi(const float* __restrict__ AP,
                                                const float* __restrict__ kappa,
                                                const float* __restrict__ AV,
                                                const int* __restrict__ alen,
                                                __hip_bfloat16* __restrict__ X2h,
                                                __hip_bfloat16* __restrict__ X2l,
                                                __hip_bfloat16* __restrict__ X3h,
                                                __hip_bfloat16* __restrict__ X3l)
{
    __shared__ float prm[4][32];
    __shared__ float phi_s[4][CHARLEN];

    const int t = threadIdx.x;
    const int wave = t >> 6;
    const int lane = t & 63;
    const int b = blockIdx.x * 4 + wave;

    if (lane < 30) {
        float p  = AP[(size_t)b * 32 + lane];
        float sp = (p > 20.f) ? p : log1pf(expf(p));
        float v;
        if (lane < 10)      v = sp;                          // alpha
        else if (lane < 20) v = fmaxf(sp, 0.01f);            // beta
        else                v = kappa[(size_t)b * NATTN + (lane - 20)] + sp * (1.f / 25.f);
        prm[wave][lane] = v;
    }
    __syncthreads();

    const int len = alen[b];
    {
        int c = lane;
        float phi = 0.f;
#pragma unroll
        for (int j = 0; j < NATTN; j++) {
            float d = prm[wave][20 + j] - (float)c;
            phi += prm[wave][j] * expf(-d * d / prm[wave][10 + j]);
        }
        phi_s[wave][c] = (c < len) ? phi : 0.f;
    }
    __syncthreads();

    for (int v0 = 0; v0 < VOCAB; v0 += 64) {
        int v = v0 + lane;
        if (v < VOCAB) {
            const float* avb = AV + (size_t)b * CHARLEN * VOCAB + v;
            float s = 0.f;
            for (int c = 0; c < len; c++)       // len is wave-uniform
                s += phi_s[wave][c] * avb[(size_t)c * VOCAB];
            __hip_bfloat16 hi, lo;
            split_bf16(s, &hi, &lo);
            X2h[(size_t)b * KP23 + 403 + v] = hi;
            X2l[(size_t)b * KP23 + 403 + v] = lo;
            X3h[(size_t)b * KP23 + 403 + v] = hi;
            X3l[(size_t)b * KP23 + 403 + v] = lo;
        }
    }
}

// ---------------------------------------------------------------- launch
extern "C" void kernel_launch(void* const* d_in, const int* in_sizes, int n_in,
                              void* d_out, int out_size, void* d_ws, size_t ws_size,
                              hipStream_t stream)
{
    const float* inputs = (const float*)d_in[0];
    const float* h1     = (const float*)d_in[1];
    const float* c1     = (const float*)d_in[2];
    const float* h2     = (const float*)d_in[3];
    const float* c2     = (const float*)d_in[4];
    const float* h3     = (const float*)d_in[5];
    const float* c3     = (const float*)d_in[6];
    const float* kappa  = (const float*)d_in[7];
    const float* w_prev = (const float*)d_in[8];
    const float* AV     = (const float*)d_in[9];
    const int*   alen   = (const int*)d_in[10];
    const float* W_ih1  = (const float*)d_in[11];
    const float* W_hh1  = (const float*)d_in[12];
    const float* b1     = (const float*)d_in[13];
    const float* W_attn = (const float*)d_in[14];
    const float* b_attn = (const float*)d_in[15];
    const float* W_ih2  = (const float*)d_in[16];
    const float* W_hh2  = (const float*)d_in[17];
    const float* b2     = (const float*)d_in[18];
    const float* W_ih3  = (const float*)d_in[19];
    const float* W_hh3  = (const float*)d_in[20];
    const float* b3     = (const float*)d_in[21];
    float* out = (float*)d_out;

    char* p = (char*)d_ws;
    __hip_bfloat16* X1h = (__hip_bfloat16*)p; p += (size_t)B_SZ * KP1 * 2;   // doubles as XA
    __hip_bfloat16* X1l = (__hip_bfloat16*)p; p += (size_t)B_SZ * KP1 * 2;
    __hip_bfloat16* X2h = (__hip_bfloat16*)p; p += (size_t)B_SZ * KP23 * 2;
    __hip_bfloat16* X2l = (__hip_bfloat16*)p; p += (size_t)B_SZ * KP23 * 2;
    __hip_bfloat16* X3h = (__hip_bfloat16*)p; p += (size_t)B_SZ * KP23 * 2;
    __hip_bfloat16* X3l = (__hip_bfloat16*)p; p += (size_t)B_SZ * KP23 * 2;
    __hip_bfloat16* W1h = (__hip_bfloat16*)p; p += (size_t)NGP * KP1 * 2;
    __hip_bfloat16* W1l = (__hip_bfloat16*)p; p += (size_t)NGP * KP1 * 2;
    __hip_bfloat16* W2h = (__hip_bfloat16*)p; p += (size_t)NGP * KP23 * 2;
    __hip_bfloat16* W2l = (__hip_bfloat16*)p; p += (size_t)NGP * KP23 * 2;
    __hip_bfloat16* W3h = (__hip_bfloat16*)p; p += (size_t)NGP * KP23 * 2;
    __hip_bfloat16* W3l = (__hip_bfloat16*)p; p += (size_t)NGP * KP23 * 2;
    __hip_bfloat16* Wah = (__hip_bfloat16*)p; p += (size_t)128 * KP1 * 2;
    __hip_bfloat16* Wal = (__hip_bfloat16*)p; p += (size_t)128 * KP1 * 2;
    float* AP = (float*)p; p += (size_t)B_SZ * 32 * 4;
    float* G  = (float*)p;  // B_SZ * NG * 4 = 26.2 MB  (total ~79.8 MB)

    pack_w<<<dim3(2, NGP), 256, 0, stream>>>(W_ih1, 76,  W_hh1, W1h, W1l, KP1);
    pack_w<<<dim3(4, NGP), 256, 0, stream>>>(W_ih2, 476, W_hh2, W2h, W2l, KP23);
    pack_w<<<dim3(4, NGP), 256, 0, stream>>>(W_ih3, 476, W_hh3, W3h, W3l, KP23);
    pack_wa<<<dim3(2, 128), 256, 0, stream>>>(W_attn, Wah, Wal);
    pack_x1<<<dim3(2, B_SZ), 256, 0, stream>>>(w_prev, inputs, h1, X1h, X1l);
    pack_x23<<<dim3(4, B_SZ), 256, 0, stream>>>(inputs, h2, h3, X2h, X2l, X3h, X3l);

    const int gates_blocks = (B_SZ * LSTM_N + 255) / 256;
    const dim3 gemm_grid(NGP / 128, B_SZ / 128);

    // LSTM1
    gemm_split<<<gemm_grid, 256, 0, stream>>>((const short*)X1h, (const short*)X1l,
                                              (const short*)W1h, (const short*)W1l,
                                              b1, G, KP1, NG, NG);
    // gates1: h1n -> X2 cols 3.. and into X1's h-region (X1 becomes attn input)
    gates_mid<<<gates_blocks, 256, 0, stream>>>(G, c1, X2h + 3, X2l + 3, KP23,
                                                X1h + 76, X1l + 76, KP1);
    // attention params GEMM: AP[4096,32] = X1 * Wa^T + b_attn
    gemm_split<<<dim3(1, B_SZ / 128), 256, 0, stream>>>((const short*)X1h, (const short*)X1l,
                                                        (const short*)Wah, (const short*)Wal,
                                                        b_attn, AP, KP1, 32, 30);
    // phi + einsum -> w into X2, X3
    attn_phi<<<B_SZ / 4, 256, 0, stream>>>(AP, kappa, AV, alen, X2h, X2l, X3h, X3l);
    // LSTM2
    gemm_split<<<gemm_grid, 256, 0, stream>>>((const short*)X2h, (const short*)X2l,
                                              (const short*)W2h, (const short*)W2l,
                                              b2, G, KP23, NG, NG);
    gates_mid<<<gates_blocks, 256, 0, stream>>>(G, c2, X3h + 3, X3l + 3, KP23,
                                                nullptr, nullptr, 0);
    // LSTM3
    gemm_split<<<gemm_grid, 256, 0, stream>>>((const short*)X3h, (const short*)X3l,
                                              (const short*)W3h, (const short*)W3l,
                                              b3, G, KP23, NG, NG);
    gates_last<<<gates_blocks, 256, 0, stream>>>(G, c3, out);
}

// Round 6
// 337.112 us; speedup vs baseline: 2.3446x; 1.1908x over previous
//
#include <hip/hip_runtime.h>
#include <hip/hip_bf16.h>

// Round 6: R5 (fp16 single-pass MFMA + XOR-swizzled LDS) with the attn_phi
// vocab-loop bug fixed (VOCAB=73 > 64 lanes needs two passes).

#define B_SZ     4096
#define LSTM_N   400
#define NG       1600   // 4*LSTM
#define NGP      1664   // padded to 13*128
#define VOCAB    73
#define NATTN    10
#define CHARLEN  64
#define KP1      480    // padded 73+3+400  (mult of 32)
#define KP23     896    // padded 3+400+73+400 (mult of 32)

typedef _Float16 half8 __attribute__((ext_vector_type(8)));
typedef __attribute__((ext_vector_type(4))) float floatx4;

__device__ __forceinline__ void gload_lds16(const void* g, void* l) {
    __builtin_amdgcn_global_load_lds(
        (const __attribute__((address_space(1))) void*)g,
        (__attribute__((address_space(3))) void*)l, 16, 0, 0);
}

// offset into a [128][32] fp16 LDS tile with XOR-swizzled 16B granules:
// physical granule within a 128B pair-line = logical ^ (pair & 7)
__device__ __forceinline__ int lds_slot(int r, int s) {
    return ((r >> 1) << 6) + (((((r & 1) << 2) | s) ^ ((r >> 1) & 7)) << 3);
}

// ---------------------------------------------------------------- pack weights
// z=0: W1 (Kp=KP1, inw=76); z=1: W2; z=2: W3 (Kp=KP23, inw=476); z=3: W_attn
__global__ __launch_bounds__(256) void pack_wall(const float* __restrict__ Wih1,
                                                 const float* __restrict__ Whh1,
                                                 const float* __restrict__ Wih2,
                                                 const float* __restrict__ Whh2,
                                                 const float* __restrict__ Wih3,
                                                 const float* __restrict__ Whh3,
                                                 const float* __restrict__ W_attn,
                                                 _Float16* __restrict__ W1,
                                                 _Float16* __restrict__ W2,
                                                 _Float16* __restrict__ W3,
                                                 _Float16* __restrict__ Wa)
{
    const int z = blockIdx.z;
    const int n = blockIdx.y;
    const int k = blockIdx.x * 256 + threadIdx.x;
    if (z == 0) {
        if (k >= KP1) return;
        float v = 0.f;
        if (n < NG) {
            if (k < 76)             v = Wih1[(size_t)n * 76 + k];
            else if (k < 476)       v = Whh1[(size_t)n * 400 + (k - 76)];
        }
        W1[(size_t)n * KP1 + k] = (_Float16)v;
    } else if (z == 1 || z == 2) {
        if (k >= KP23) return;
        const float* Wih = (z == 1) ? Wih2 : Wih3;
        const float* Whh = (z == 1) ? Whh2 : Whh3;
        float v = 0.f;
        if (n < NG) {
            if (k < 476)            v = Wih[(size_t)n * 476 + k];
            else if (k < 876)       v = Whh[(size_t)n * 400 + (k - 476)];
        }
        ((z == 1) ? W2 : W3)[(size_t)n * KP23 + k] = (_Float16)v;
    } else {
        if (n >= 128 || k >= KP1) return;
        float v = (n < 30 && k < 476) ? W_attn[(size_t)n * 476 + k] : 0.f;
        Wa[(size_t)n * KP1 + k] = (_Float16)v;
    }
}

// ---------------------------------------------------------------- pack X1/X2/X3
// X1 = [w_prev(73)|inputs(3)|h1(400)|0]; X2/X3 = [inputs(3)|<later>|h(400)|0]
__global__ __launch_bounds__(256) void pack_x(const float* __restrict__ w_prev,
                                              const float* __restrict__ inputs,
                                              const float* __restrict__ h1,
                                              const float* __restrict__ h2,
                                              const float* __restrict__ h3,
                                              _Float16* __restrict__ X1,
                                              _Float16* __restrict__ X2,
                                              _Float16* __restrict__ X3)
{
    const int b = blockIdx.y;
    const int k = blockIdx.x * 256 + threadIdx.x;
    if (k < KP1) {
        float v = 0.f;
        if (k < 73)        v = w_prev[(size_t)b * 73 + k];
        else if (k < 76)   v = inputs[(size_t)b * 3 + (k - 73)];
        else if (k < 476)  v = h1[(size_t)b * 400 + (k - 76)];
        X1[(size_t)b * KP1 + k] = (_Float16)v;
    }
    const int kk = k - KP1;
    if (kk >= 0 && kk < KP23) {
        if (kk >= 3 && kk < 476) return;   // h1n/h2n by gates, w by attn
        float v2 = 0.f, v3 = 0.f;
        if (kk < 3) { v2 = inputs[(size_t)b * 3 + kk]; v3 = v2; }
        else if (kk >= 476 && kk < 876) {
            v2 = h2[(size_t)b * 400 + (kk - 476)];
            v3 = h3[(size_t)b * 400 + (kk - 476)];
        }
        X2[(size_t)b * KP23 + kk] = (_Float16)v2;
        X3[(size_t)b * KP23 + kk] = (_Float16)v3;
    }
}

// ---------------------------------------------------------------- fp16 GEMM
// C[m,n] = sum_k A[m,k]*Bw[n,k] + bias[n]; 128x128 tile, 2x2 waves, 4x4 frags.
__global__ __launch_bounds__(256) void gemm_f16(const _Float16* __restrict__ A,
                                                const _Float16* __restrict__ Bw,
                                                const float* __restrict__ bias,
                                                float* __restrict__ C, int Kp,
                                                int ldC, int Nvalid)
{
    __shared__ _Float16 As[128 * 32];   // 8 KB, XOR-swizzled granules
    __shared__ _Float16 Bs[128 * 32];

    const int t    = threadIdx.x;
    const int w    = t >> 6;
    const int lane = t & 63;
    const int quad = lane >> 4;
    const int l16  = lane & 15;
    const int m0   = blockIdx.y * 128;
    const int n0   = blockIdx.x * 128;
    const int wm   = (w >> 1) * 64;
    const int wn   = (w & 1) * 64;
    // swizzled staging source for this lane (within a 16-row chunk):
    const int pr   = lane >> 3;              // pair 0..7
    const int sw8  = (lane & 7) ^ pr;        // logical granule this lane fetches
    const int rowo = (pr << 1) + (sw8 >> 2); // row offset 0..15
    const int ko   = (sw8 & 3) << 3;         // k element offset 0,8,16,24

    floatx4 acc[4][4] = {};

    for (int k0 = 0; k0 < Kp; k0 += 32) {
        __syncthreads();
#pragma unroll
        for (int j = 0; j < 2; j++) {
            const int cr = (j * 4 + w) * 16;   // wave-uniform chunk row
            gload_lds16(A  + (size_t)(m0 + cr + rowo) * Kp + k0 + ko, As + cr * 32);
            gload_lds16(Bw + (size_t)(n0 + cr + rowo) * Kp + k0 + ko, Bs + cr * 32);
        }
        asm volatile("s_waitcnt vmcnt(0)" ::: "memory");
        __syncthreads();

        half8 af[4], bf[4];
#pragma unroll
        for (int i = 0; i < 4; i++) {
            af[i] = *(const half8*)(As + lds_slot(wm + i * 16 + l16, quad));
            bf[i] = *(const half8*)(Bs + lds_slot(wn + i * 16 + l16, quad));
        }
#pragma unroll
        for (int mt = 0; mt < 4; mt++)
#pragma unroll
            for (int nt = 0; nt < 4; nt++)
                acc[mt][nt] = __builtin_amdgcn_mfma_f32_16x16x32_f16(
                    af[mt], bf[nt], acc[mt][nt], 0, 0, 0);
    }

#pragma unroll
    for (int nt = 0; nt < 4; nt++) {
        const int n = n0 + wn + nt * 16 + l16;
        if (n >= Nvalid) continue;
        const float bv = bias[n];
#pragma unroll
        for (int mt = 0; mt < 4; mt++) {
            const int mbase = m0 + wm + mt * 16 + quad * 4;
#pragma unroll
            for (int r = 0; r < 4; r++)
                C[(size_t)(mbase + r) * ldC + n] = acc[mt][nt][r] + bv;
        }
    }
}

// ---------------------------------------------------------------- LSTM gates
__global__ __launch_bounds__(256) void gates_mid(const float* __restrict__ G,
                                                 const float* __restrict__ c_in,
                                                 _Float16* __restrict__ d1, int ld1,
                                                 _Float16* __restrict__ d2, int ld2)
{
    int id = blockIdx.x * 256 + threadIdx.x;
    if (id >= B_SZ * LSTM_N) return;
    int b = id / LSTM_N;
    int u = id - b * LSTM_N;
    const float* g = G + (size_t)b * NG;
    float gi = g[u], gf = g[LSTM_N + u], gc = g[2 * LSTM_N + u], go = g[3 * LSTM_N + u];
    float si = 1.f / (1.f + expf(-gi));
    float sf = 1.f / (1.f + expf(-gf));
    float so = 1.f / (1.f + expf(-go));
    float cn = sf * c_in[id] + si * tanhf(gc);
    float h  = so * tanhf(cn);
    _Float16 hh = (_Float16)h;
    d1[(size_t)b * ld1 + u] = hh;
    if (d2) d2[(size_t)b * ld2 + u] = hh;
}

__global__ __launch_bounds__(256) void gates_last(const float* __restrict__ G,
                                                  const float* __restrict__ c_in,
                                                  float* __restrict__ out)
{
    int id = blockIdx.x * 256 + threadIdx.x;
    if (id >= B_SZ * LSTM_N) return;
    int b = id / LSTM_N;
    int u = id - b * LSTM_N;
    const float* g = G + (size_t)b * NG;
    float gi = g[u], gf = g[LSTM_N + u], gc = g[2 * LSTM_N + u], go = g[3 * LSTM_N + u];
    float si = 1.f / (1.f + expf(-gi));
    float sf = 1.f / (1.f + expf(-gf));
    float so = 1.f / (1.f + expf(-go));
    float cn = sf * c_in[id] + si * tanhf(gc);
    out[id]  = so * tanhf(cn);
}

// ---------------------------------------------------------------- attn phi+w
// wave = one batch row; 4 waves/block; grid B/4.
__global__ __launch_bounds__(256) void attn_phi(const float* __restrict__ AP,
                                                const float* __restrict__ kappa,
                                                const float* __restrict__ AV,
                                                const int* __restrict__ alen,
                                                _Float16* __restrict__ X2,
                                                _Float16* __restrict__ X3)
{
    __shared__ float prm[4][32];
    __shared__ float phi_s[4][CHARLEN];

    const int t = threadIdx.x;
    const int wave = t >> 6;
    const int lane = t & 63;
    const int b = blockIdx.x * 4 + wave;

    if (lane < 30) {
        float p  = AP[(size_t)b * 32 + lane];
        float sp = (p > 20.f) ? p : log1pf(expf(p));
        float v;
        if (lane < 10)      v = sp;                          // alpha
        else if (lane < 20) v = fmaxf(sp, 0.01f);            // beta
        else                v = kappa[(size_t)b * NATTN + (lane - 20)] + sp * (1.f / 25.f);
        prm[wave][lane] = v;
    }
    __syncthreads();

    const int len = alen[b];
    {
        int c = lane;
        float phi = 0.f;
#pragma unroll
        for (int j = 0; j < NATTN; j++) {
            float d = prm[wave][20 + j] - (float)c;
            phi += prm[wave][j] * expf(-d * d / prm[wave][10 + j]);
        }
        phi_s[wave][c] = (c < len) ? phi : 0.f;
    }
    __syncthreads();

    // VOCAB=73 > 64 lanes: two passes (lane and lane+64)
    for (int v0 = 0; v0 < VOCAB; v0 += 64) {
        const int v = v0 + lane;
        if (v < VOCAB) {
            const float* avb = AV + (size_t)b * CHARLEN * VOCAB + v;
            float s = 0.f;
            for (int c = 0; c < len; c++)      // len is wave-uniform
                s += phi_s[wave][c] * avb[(size_t)c * VOCAB];
            _Float16 wv = (_Float16)s;
            X2[(size_t)b * KP23 + 403 + v] = wv;
            X3[(size_t)b * KP23 + 403 + v] = wv;
        }
    }
}

// ---------------------------------------------------------------- launch
extern "C" void kernel_launch(void* const* d_in, const int* in_sizes, int n_in,
                              void* d_out, int out_size, void* d_ws, size_t ws_size,
                              hipStream_t stream)
{
    const float* inputs = (const float*)d_in[0];
    const float* h1     = (const float*)d_in[1];
    const float* c1     = (const float*)d_in[2];
    const float* h2     = (const float*)d_in[3];
    const float* c2     = (const float*)d_in[4];
    const float* h3     = (const float*)d_in[5];
    const float* c3     = (const float*)d_in[6];
    const float* kappa  = (const float*)d_in[7];
    const float* w_prev = (const float*)d_in[8];
    const float* AV     = (const float*)d_in[9];
    const int*   alen   = (const int*)d_in[10];
    const float* W_ih1  = (const float*)d_in[11];
    const float* W_hh1  = (const float*)d_in[12];
    const float* b1     = (const float*)d_in[13];
    const float* W_attn = (const float*)d_in[14];
    const float* b_attn = (const float*)d_in[15];
    const float* W_ih2  = (const float*)d_in[16];
    const float* W_hh2  = (const float*)d_in[17];
    const float* b2     = (const float*)d_in[18];
    const float* W_ih3  = (const float*)d_in[19];
    const float* W_hh3  = (const float*)d_in[20];
    const float* b3     = (const float*)d_in[21];
    float* out = (float*)d_out;

    char* p = (char*)d_ws;
    _Float16* X1 = (_Float16*)p; p += (size_t)B_SZ * KP1 * 2;   // becomes attn input
    _Float16* X2 = (_Float16*)p; p += (size_t)B_SZ * KP23 * 2;
    _Float16* X3 = (_Float16*)p; p += (size_t)B_SZ * KP23 * 2;
    _Float16* W1 = (_Float16*)p; p += (size_t)NGP * KP1 * 2;
    _Float16* W2 = (_Float16*)p; p += (size_t)NGP * KP23 * 2;
    _Float16* W3 = (_Float16*)p; p += (size_t)NGP * KP23 * 2;
    _Float16* Wa = (_Float16*)p; p += (size_t)128 * KP1 * 2;
    float* AP = (float*)p; p += (size_t)B_SZ * 32 * 4;
    float* G  = (float*)p;  // B_SZ * NG * 4 = 26.2 MB (total ~53 MB)

    pack_wall<<<dim3(4, NGP, 4), 256, 0, stream>>>(W_ih1, W_hh1, W_ih2, W_hh2,
                                                   W_ih3, W_hh3, W_attn,
                                                   W1, W2, W3, Wa);
    pack_x<<<dim3((KP1 + KP23 + 255) / 256, B_SZ), 256, 0, stream>>>(
        w_prev, inputs, h1, h2, h3, X1, X2, X3);

    const int gates_blocks = (B_SZ * LSTM_N + 255) / 256;
    const dim3 gemm_grid(NGP / 128, B_SZ / 128);

    // LSTM1
    gemm_f16<<<gemm_grid, 256, 0, stream>>>(X1, W1, b1, G, KP1, NG, NG);
    // gates1: h1n -> X2 cols 3.. and into X1's h-region (X1 becomes attn input)
    gates_mid<<<gates_blocks, 256, 0, stream>>>(G, c1, X2 + 3, KP23, X1 + 76, KP1);
    // attention params: AP[4096,32] = X1 * Wa^T + b_attn
    gemm_f16<<<dim3(1, B_SZ / 128), 256, 0, stream>>>(X1, Wa, b_attn, AP, KP1, 32, 30);
    // phi + einsum -> w into X2, X3
    attn_phi<<<B_SZ / 4, 256, 0, stream>>>(AP, kappa, AV, alen, X2, X3);
    // LSTM2
    gemm_f16<<<gemm_grid, 256, 0, stream>>>(X2, W2, b2, G, KP23, NG, NG);
    gates_mid<<<gates_blocks, 256, 0, stream>>>(G, c2, X3 + 3, KP23, nullptr, 0);
    // LSTM3
    gemm_f16<<<gemm_grid, 256, 0, stream>>>(X3, W3, b3, G, KP23, NG, NG);
    gates_last<<<gates_blocks, 256, 0, stream>>>(G, c3, out);
}

// Round 7
// 323.143 us; speedup vs baseline: 2.4459x; 1.0432x over previous
//
#include <hip/hip_runtime.h>
#include <hip/hip_bf16.h>

// Round 7: transposed GEMM (C^T = W·X^T) with gate-interleaved weight rows
// (row 4u+g) so each lane's 4 accumulator regs hold the 4 gates of one unit:
// LSTM pointwise fused into the GEMM epilogue, G never materialized, gates
// kernels deleted. Attention gets its own XA buffer (no write-into-input race).

#define B_SZ     4096
#define LSTM_N   400
#define NG       1600   // 4*LSTM
#define NGP      1664   // padded to 13*128
#define VOCAB    73
#define NATTN    10
#define CHARLEN  64
#define KP1      480    // padded 73+3+400  (mult of 32)
#define KP23     896    // padded 3+400+73+400 (mult of 32)

typedef _Float16 half8 __attribute__((ext_vector_type(8)));
typedef __attribute__((ext_vector_type(4))) float floatx4;

__device__ __forceinline__ void gload_lds16(const void* g, void* l) {
    __builtin_amdgcn_global_load_lds(
        (const __attribute__((address_space(1))) void*)g,
        (__attribute__((address_space(3))) void*)l, 16, 0, 0);
}

// offset into a [128][32] fp16 LDS tile with XOR-swizzled 16B granules:
// physical granule within a 128B pair-line = logical ^ (pair & 7)
__device__ __forceinline__ int lds_slot(int r, int s) {
    return ((r >> 1) << 6) + (((((r & 1) << 2) | s) ^ ((r >> 1) & 7)) << 3);
}

// ---------------------------------------------------------------- pack weights
// z=0: W1 interleaved (Kp=KP1); z=1: W2; z=2: W3 (Kp=KP23); z=3: W_attn plain.
// Interleave: dest row n' = 4u+g  <-  src row g*400+u.
__global__ __launch_bounds__(256) void pack_wall(const float* __restrict__ Wih1,
                                                 const float* __restrict__ Whh1,
                                                 const float* __restrict__ Wih2,
                                                 const float* __restrict__ Whh2,
                                                 const float* __restrict__ Wih3,
                                                 const float* __restrict__ Whh3,
                                                 const float* __restrict__ W_attn,
                                                 _Float16* __restrict__ W1,
                                                 _Float16* __restrict__ W2,
                                                 _Float16* __restrict__ W3,
                                                 _Float16* __restrict__ Wa)
{
    const int z = blockIdx.z;
    const int n = blockIdx.y;           // dest row
    const int k = blockIdx.x * 256 + threadIdx.x;
    if (z == 3) {
        if (n >= 128 || k >= KP1) return;
        float v = (n < 30 && k < 476) ? W_attn[(size_t)n * 476 + k] : 0.f;
        Wa[(size_t)n * KP1 + k] = (_Float16)v;
        return;
    }
    const int u = n >> 2, g = n & 3;
    const int src = g * 400 + u;        // original torch row
    if (z == 0) {
        if (k >= KP1) return;
        float v = 0.f;
        if (u < 400) {
            if (k < 76)           v = Wih1[(size_t)src * 76 + k];
            else if (k < 476)     v = Whh1[(size_t)src * 400 + (k - 76)];
        }
        W1[(size_t)n * KP1 + k] = (_Float16)v;
    } else {
        if (k >= KP23) return;
        const float* Wih = (z == 1) ? Wih2 : Wih3;
        const float* Whh = (z == 1) ? Whh2 : Whh3;
        float v = 0.f;
        if (u < 400) {
            if (k < 476)          v = Wih[(size_t)src * 476 + k];
            else if (k < 876)     v = Whh[(size_t)src * 400 + (k - 476)];
        }
        ((z == 1) ? W2 : W3)[(size_t)n * KP23 + k] = (_Float16)v;
    }
}

// ---------------------------------------------------------------- pack X/XA
// X1 = [w_prev|inputs|h1|0]; XA = [w_prev|inputs|(h1n later)|0];
// X2/X3 = [inputs|(h later)|(w later)|h2/h3|0]
__global__ __launch_bounds__(256) void pack_x(const float* __restrict__ w_prev,
                                              const float* __restrict__ inputs,
                                              const float* __restrict__ h1,
                                              const float* __restrict__ h2,
                                              const float* __restrict__ h3,
                                              _Float16* __restrict__ X1,
                                              _Float16* __restrict__ XA,
                                              _Float16* __restrict__ X2,
                                              _Float16* __restrict__ X3)
{
    const int b = blockIdx.y;
    const int k = blockIdx.x * 256 + threadIdx.x;
    if (k < KP1) {
        float v = 0.f;
        if (k < 73)        v = w_prev[(size_t)b * 73 + k];
        else if (k < 76)   v = inputs[(size_t)b * 3 + (k - 73)];
        else if (k < 476)  v = h1[(size_t)b * 400 + (k - 76)];
        X1[(size_t)b * KP1 + k] = (_Float16)v;
        if (k < 76 || k >= 476) XA[(size_t)b * KP1 + k] = (_Float16)v;
    }
    const int kk = k - KP1;
    if (kk >= 0 && kk < KP23) {
        if (kk >= 3 && kk < 476) return;   // h1n/h2n by epilogue, w by attn
        float v2 = 0.f, v3 = 0.f;
        if (kk < 3) { v2 = inputs[(size_t)b * 3 + kk]; v3 = v2; }
        else if (kk >= 476 && kk < 876) {
            v2 = h2[(size_t)b * 400 + (kk - 476)];
            v3 = h3[(size_t)b * 400 + (kk - 476)];
        }
        X2[(size_t)b * KP23 + kk] = (_Float16)v2;
        X3[(size_t)b * KP23 + kk] = (_Float16)v3;
    }
}

// ---------------------------------------------------------------- fused GEMM
// C[m,n] = sum_k Wm[m,k]*X[n,k] ; m = 4u+g (interleaved gate rows), n = batch.
// Epilogue: lane regs r=0..3 = gates i,f,g,o of unit u -> LSTM pointwise ->
// h stored fp16 to d1/d2 (ld elements) or fp32 to fout.
__global__ __launch_bounds__(256) void gemm_fused(const _Float16* __restrict__ Wm,
                                                  const _Float16* __restrict__ X,
                                                  const float* __restrict__ bias,
                                                  const float* __restrict__ c_in,
                                                  _Float16* __restrict__ d1, int ld1,
                                                  _Float16* __restrict__ d2, int ld2,
                                                  float* __restrict__ fout, int Kp)
{
    __shared__ _Float16 As[128 * 32];   // W tile, XOR-swizzled
    __shared__ _Float16 Bs[128 * 32];   // X tile

    const int t    = threadIdx.x;
    const int w    = t >> 6;
    const int lane = t & 63;
    const int quad = lane >> 4;
    const int l16  = lane & 15;
    const int m0   = blockIdx.y * 128;  // weight-row tile
    const int n0   = blockIdx.x * 128;  // batch tile
    const int wm   = (w >> 1) * 64;
    const int wn   = (w & 1) * 64;
    const int pr   = lane >> 3;
    const int sw8  = (lane & 7) ^ pr;
    const int rowo = (pr << 1) + (sw8 >> 2);
    const int ko   = (sw8 & 3) << 3;

    floatx4 acc[4][4] = {};

    for (int k0 = 0; k0 < Kp; k0 += 32) {
        __syncthreads();
#pragma unroll
        for (int j = 0; j < 2; j++) {
            const int cr = (j * 4 + w) * 16;
            gload_lds16(Wm + (size_t)(m0 + cr + rowo) * Kp + k0 + ko, As + cr * 32);
            gload_lds16(X  + (size_t)(n0 + cr + rowo) * Kp + k0 + ko, Bs + cr * 32);
        }
        asm volatile("s_waitcnt vmcnt(0)" ::: "memory");
        __syncthreads();

        half8 af[4], bf[4];
#pragma unroll
        for (int i = 0; i < 4; i++) {
            af[i] = *(const half8*)(As + lds_slot(wm + i * 16 + l16, quad));
            bf[i] = *(const half8*)(Bs + lds_slot(wn + i * 16 + l16, quad));
        }
#pragma unroll
        for (int mt = 0; mt < 4; mt++)
#pragma unroll
            for (int nt = 0; nt < 4; nt++)
                acc[mt][nt] = __builtin_amdgcn_mfma_f32_16x16x32_f16(
                    af[mt], bf[nt], acc[mt][nt], 0, 0, 0);
    }

#pragma unroll
    for (int mt = 0; mt < 4; mt++) {
        const int u = ((m0 + wm + mt * 16) >> 2) + quad;   // unit index
        if (u >= LSTM_N) continue;
        const float bi = bias[u];
        const float bff = bias[400 + u];
        const float bg = bias[800 + u];
        const float bo = bias[1200 + u];
#pragma unroll
        for (int nt = 0; nt < 4; nt++) {
            const int b = n0 + wn + nt * 16 + l16;         // batch index
            float gi = acc[mt][nt][0] + bi;
            float gf = acc[mt][nt][1] + bff;
            float gg = acc[mt][nt][2] + bg;
            float go = acc[mt][nt][3] + bo;
            float si = 1.f / (1.f + expf(-gi));
            float sf = 1.f / (1.f + expf(-gf));
            float so = 1.f / (1.f + expf(-go));
            float cn = sf * c_in[(size_t)b * LSTM_N + u] + si * tanhf(gg);
            float h  = so * tanhf(cn);
            if (fout) {
                fout[(size_t)b * LSTM_N + u] = h;
            } else {
                _Float16 hh = (_Float16)h;
                d1[(size_t)b * ld1 + u] = hh;
                if (d2) d2[(size_t)b * ld2 + u] = hh;
            }
        }
    }
}

// ---------------------------------------------------------------- plain GEMM
// (attention params only) C[m,n] = sum_k A[m,k]*Bw[n,k] + bias[n]
__global__ __launch_bounds__(256) void gemm_plain(const _Float16* __restrict__ A,
                                                  const _Float16* __restrict__ Bw,
                                                  const float* __restrict__ bias,
                                                  float* __restrict__ C, int Kp,
                                                  int ldC, int Nvalid)
{
    __shared__ _Float16 As[128 * 32];
    __shared__ _Float16 Bs[128 * 32];

    const int t    = threadIdx.x;
    const int w    = t >> 6;
    const int lane = t & 63;
    const int quad = lane >> 4;
    const int l16  = lane & 15;
    const int m0   = blockIdx.y * 128;
    const int n0   = blockIdx.x * 128;
    const int wm   = (w >> 1) * 64;
    const int wn   = (w & 1) * 64;
    const int pr   = lane >> 3;
    const int sw8  = (lane & 7) ^ pr;
    const int rowo = (pr << 1) + (sw8 >> 2);
    const int ko   = (sw8 & 3) << 3;

    floatx4 acc[4][4] = {};

    for (int k0 = 0; k0 < Kp; k0 += 32) {
        __syncthreads();
#pragma unroll
        for (int j = 0; j < 2; j++) {
            const int cr = (j * 4 + w) * 16;
            gload_lds16(A  + (size_t)(m0 + cr + rowo) * Kp + k0 + ko, As + cr * 32);
            gload_lds16(Bw + (size_t)(n0 + cr + rowo) * Kp + k0 + ko, Bs + cr * 32);
        }
        asm volatile("s_waitcnt vmcnt(0)" ::: "memory");
        __syncthreads();

        half8 af[4], bf[4];
#pragma unroll
        for (int i = 0; i < 4; i++) {
            af[i] = *(const half8*)(As + lds_slot(wm + i * 16 + l16, quad));
            bf[i] = *(const half8*)(Bs + lds_slot(wn + i * 16 + l16, quad));
        }
#pragma unroll
        for (int mt = 0; mt < 4; mt++)
#pragma unroll
            for (int nt = 0; nt < 4; nt++)
                acc[mt][nt] = __builtin_amdgcn_mfma_f32_16x16x32_f16(
                    af[mt], bf[nt], acc[mt][nt], 0, 0, 0);
    }

#pragma unroll
    for (int nt = 0; nt < 4; nt++) {
        const int n = n0 + wn + nt * 16 + l16;
        if (n >= Nvalid) continue;
        const float bv = bias[n];
#pragma unroll
        for (int mt = 0; mt < 4; mt++) {
            const int mbase = m0 + wm + mt * 16 + quad * 4;
#pragma unroll
            for (int r = 0; r < 4; r++)
                C[(size_t)(mbase + r) * ldC + n] = acc[mt][nt][r] + bv;
        }
    }
}

// ---------------------------------------------------------------- attn phi+w
// wave = one batch row; 4 waves/block; grid B/4.
__global__ __launch_bounds__(256) void attn_phi(const float* __restrict__ AP,
                                                const float* __restrict__ kappa,
                                                const float* __restrict__ AV,
                                                const int* __restrict__ alen,
                                                _Float16* __restrict__ X2,
                                                _Float16* __restrict__ X3)
{
    __shared__ float prm[4][32];
    __shared__ float phi_s[4][CHARLEN];

    const int t = threadIdx.x;
    const int wave = t >> 6;
    const int lane = t & 63;
    const int b = blockIdx.x * 4 + wave;

    if (lane < 30) {
        float p  = AP[(size_t)b * 32 + lane];
        float sp = (p > 20.f) ? p : log1pf(expf(p));
        float v;
        if (lane < 10)      v = sp;                          // alpha
        else if (lane < 20) v = fmaxf(sp, 0.01f);            // beta
        else                v = kappa[(size_t)b * NATTN + (lane - 20)] + sp * (1.f / 25.f);
        prm[wave][lane] = v;
    }
    __syncthreads();

    const int len = alen[b];
    {
        int c = lane;
        float phi = 0.f;
#pragma unroll
        for (int j = 0; j < NATTN; j++) {
            float d = prm[wave][20 + j] - (float)c;
            phi += prm[wave][j] * expf(-d * d / prm[wave][10 + j]);
        }
        phi_s[wave][c] = (c < len) ? phi : 0.f;
    }
    __syncthreads();

    for (int v0 = 0; v0 < VOCAB; v0 += 64) {   // VOCAB=73 > 64 lanes
        const int v = v0 + lane;
        if (v < VOCAB) {
            const float* avb = AV + (size_t)b * CHARLEN * VOCAB + v;
            float s = 0.f;
            for (int c = 0; c < len; c++)      // len is wave-uniform
                s += phi_s[wave][c] * avb[(size_t)c * VOCAB];
            _Float16 wv = (_Float16)s;
            X2[(size_t)b * KP23 + 403 + v] = wv;
            X3[(size_t)b * KP23 + 403 + v] = wv;
        }
    }
}

// ---------------------------------------------------------------- launch
extern "C" void kernel_launch(void* const* d_in, const int* in_sizes, int n_in,
                              void* d_out, int out_size, void* d_ws, size_t ws_size,
                              hipStream_t stream)
{
    const float* inputs = (const float*)d_in[0];
    const float* h1     = (const float*)d_in[1];
    const float* c1     = (const float*)d_in[2];
    const float* h2     = (const float*)d_in[3];
    const float* c2     = (const float*)d_in[4];
    const float* h3     = (const float*)d_in[5];
    const float* c3     = (const float*)d_in[6];
    const float* kappa  = (const float*)d_in[7];
    const float* w_prev = (const float*)d_in[8];
    const float* AV     = (const float*)d_in[9];
    const int*   alen   = (const int*)d_in[10];
    const float* W_ih1  = (const float*)d_in[11];
    const float* W_hh1  = (const float*)d_in[12];
    const float* b1     = (const float*)d_in[13];
    const float* W_attn = (const float*)d_in[14];
    const float* b_attn = (const float*)d_in[15];
    const float* W_ih2  = (const float*)d_in[16];
    const float* W_hh2  = (const float*)d_in[17];
    const float* b2     = (const float*)d_in[18];
    const float* W_ih3  = (const float*)d_in[19];
    const float* W_hh3  = (const float*)d_in[20];
    const float* b3     = (const float*)d_in[21];
    float* out = (float*)d_out;

    char* p = (char*)d_ws;
    _Float16* X1 = (_Float16*)p; p += (size_t)B_SZ * KP1 * 2;
    _Float16* XA = (_Float16*)p; p += (size_t)B_SZ * KP1 * 2;   // attn input
    _Float16* X2 = (_Float16*)p; p += (size_t)B_SZ * KP23 * 2;
    _Float16* X3 = (_Float16*)p; p += (size_t)B_SZ * KP23 * 2;
    _Float16* W1 = (_Float16*)p; p += (size_t)NGP * KP1 * 2;
    _Float16* W2 = (_Float16*)p; p += (size_t)NGP * KP23 * 2;
    _Float16* W3 = (_Float16*)p; p += (size_t)NGP * KP23 * 2;
    _Float16* Wa = (_Float16*)p; p += (size_t)128 * KP1 * 2;
    float* AP = (float*)p;                                       // B*32 fp32

    pack_wall<<<dim3(4, NGP, 4), 256, 0, stream>>>(W_ih1, W_hh1, W_ih2, W_hh2,
                                                   W_ih3, W_hh3, W_attn,
                                                   W1, W2, W3, Wa);
    pack_x<<<dim3((KP1 + KP23 + 255) / 256, B_SZ), 256, 0, stream>>>(
        w_prev, inputs, h1, h2, h3, X1, XA, X2, X3);

    const dim3 fgrid(B_SZ / 128, NGP / 128);   // x: batch tiles, y: gate-row tiles

    // LSTM1: h1n -> XA h-region (attn input) + X2 cols 3..
    gemm_fused<<<fgrid, 256, 0, stream>>>(W1, X1, b1, c1,
                                          XA + 76, KP1, X2 + 3, KP23, nullptr, KP1);
    // attention params: AP[4096,32] = XA * Wa^T + b_attn
    gemm_plain<<<dim3(1, B_SZ / 128), 256, 0, stream>>>(XA, Wa, b_attn, AP, KP1, 32, 30);
    // phi + einsum -> w into X2, X3
    attn_phi<<<B_SZ / 4, 256, 0, stream>>>(AP, kappa, AV, alen, X2, X3);
    // LSTM2: h2n -> X3 cols 3..
    gemm_fused<<<fgrid, 256, 0, stream>>>(W2, X2, b2, c2,
                                          X3 + 3, KP23, nullptr, 0, nullptr, KP23);
    // LSTM3: h3n -> out (fp32)
    gemm_fused<<<fgrid, 256, 0, stream>>>(W3, X3, b3, c3,
                                          nullptr, 0, nullptr, 0, out, KP23);
}

// Round 8
// 297.373 us; speedup vs baseline: 2.6579x; 1.0867x over previous
//
#include <hip/hip_runtime.h>
#include <hip/hip_bf16.h>

// Round 8: fused-epilogue fp16 MFMA GEMM restructured for occupancy:
//   - 64(gate-rows) x 128(batch) tiles -> grid 25x32 = 800 blocks (3.1/CU,
//     ~12.5 waves/CU) so wave-level MFMA/staging overlap can happen
//   - BK=64 (14 iters at K=896) halves barrier drains; KP1 padded to 512
//   - XOR swizzle for [row][64] fp16 tiles: phys granule = logical ^ (row&7)

#define B_SZ     4096
#define LSTM_N   400
#define NG       1600   // 4*LSTM
#define VOCAB    73
#define NATTN    10
#define CHARLEN  64
#define KP1      512    // padded 73+3+400  (mult of 64)
#define KP23     896    // padded 3+400+73+400 (mult of 64)

typedef _Float16 half8 __attribute__((ext_vector_type(8)));
typedef __attribute__((ext_vector_type(4))) float floatx4;

__device__ __forceinline__ void gload_lds16(const void* g, void* l) {
    __builtin_amdgcn_global_load_lds(
        (const __attribute__((address_space(1))) void*)g,
        (__attribute__((address_space(3))) void*)l, 16, 0, 0);
}

// [row][64-half] LDS tile, XOR-swizzled 16B granules within each 128B row:
// physical granule = logical granule ^ (row & 7)
__device__ __forceinline__ int lds_off(int r, int g) {
    return (r << 6) + ((((g ^ r) & 7)) << 3);
}

// ---------------------------------------------------------------- pack weights
// z=0: W1 gate-interleaved (Kp=512); z=1: W2; z=2: W3 (Kp=896); z=3: W_attn.
// Interleave: dest row n = 4u+g  <-  src row g*400+u.
__global__ __launch_bounds__(256) void pack_wall(const float* __restrict__ Wih1,
                                                 const float* __restrict__ Whh1,
                                                 const float* __restrict__ Wih2,
                                                 const float* __restrict__ Whh2,
                                                 const float* __restrict__ Wih3,
                                                 const float* __restrict__ Whh3,
                                                 const float* __restrict__ W_attn,
                                                 _Float16* __restrict__ W1,
                                                 _Float16* __restrict__ W2,
                                                 _Float16* __restrict__ W3,
                                                 _Float16* __restrict__ Wa)
{
    const int z = blockIdx.z;
    const int n = blockIdx.y;           // dest row
    const int k = blockIdx.x * 256 + threadIdx.x;
    if (z == 3) {
        if (n >= 64 || k >= KP1) return;
        float v = (n < 30 && k < 476) ? W_attn[(size_t)n * 476 + k] : 0.f;
        Wa[(size_t)n * KP1 + k] = (_Float16)v;
        return;
    }
    if (n >= NG) return;
    const int u = n >> 2, g = n & 3;
    const int src = g * 400 + u;        // original torch row
    if (z == 0) {
        if (k >= KP1) return;
        float v = 0.f;
        if (k < 76)           v = Wih1[(size_t)src * 76 + k];
        else if (k < 476)     v = Whh1[(size_t)src * 400 + (k - 76)];
        W1[(size_t)n * KP1 + k] = (_Float16)v;
    } else {
        if (k >= KP23) return;
        const float* Wih = (z == 1) ? Wih2 : Wih3;
        const float* Whh = (z == 1) ? Whh2 : Whh3;
        float v = 0.f;
        if (k < 476)          v = Wih[(size_t)src * 476 + k];
        else if (k < 876)     v = Whh[(size_t)src * 400 + (k - 476)];
        ((z == 1) ? W2 : W3)[(size_t)n * KP23 + k] = (_Float16)v;
    }
}

// ---------------------------------------------------------------- pack X/XA
__global__ __launch_bounds__(256) void pack_x(const float* __restrict__ w_prev,
                                              const float* __restrict__ inputs,
                                              const float* __restrict__ h1,
                                              const float* __restrict__ h2,
                                              const float* __restrict__ h3,
                                              _Float16* __restrict__ X1,
                                              _Float16* __restrict__ XA,
                                              _Float16* __restrict__ X2,
                                              _Float16* __restrict__ X3)
{
    const int b = blockIdx.y;
    const int k = blockIdx.x * 256 + threadIdx.x;
    if (k < KP1) {
        float v = 0.f;
        if (k < 73)        v = w_prev[(size_t)b * 73 + k];
        else if (k < 76)   v = inputs[(size_t)b * 3 + (k - 73)];
        else if (k < 476)  v = h1[(size_t)b * 400 + (k - 76)];
        X1[(size_t)b * KP1 + k] = (_Float16)v;
        if (k < 76 || k >= 476) XA[(size_t)b * KP1 + k] = (_Float16)v;
    }
    const int kk = k - KP1;
    if (kk >= 0 && kk < KP23) {
        if (kk >= 3 && kk < 476) return;   // h1n/h2n by epilogue, w by attn
        float v2 = 0.f, v3 = 0.f;
        if (kk < 3) { v2 = inputs[(size_t)b * 3 + kk]; v3 = v2; }
        else if (kk >= 476 && kk < 876) {
            v2 = h2[(size_t)b * 400 + (kk - 476)];
            v3 = h3[(size_t)b * 400 + (kk - 476)];
        }
        X2[(size_t)b * KP23 + kk] = (_Float16)v2;
        X3[(size_t)b * KP23 + kk] = (_Float16)v3;
    }
}

// ---------------------------------------------------------------- fused GEMM
// 64x128 tile: m = gate rows (4u+g interleaved), n = batch. BK=64.
// Waves 2x2: each wave 32 rows x 64 batch = 2x4 frags.
// Epilogue: lane regs 0..3 = gates i,f,g,o of unit u -> LSTM pointwise.
__global__ __launch_bounds__(256) void gemm_fused(const _Float16* __restrict__ Wm,
                                                  const _Float16* __restrict__ X,
                                                  const float* __restrict__ bias,
                                                  const float* __restrict__ c_in,
                                                  _Float16* __restrict__ d1, int ld1,
                                                  _Float16* __restrict__ d2, int ld2,
                                                  float* __restrict__ fout, int Kp)
{
    __shared__ _Float16 As[64 * 64];    // W tile, 8 KB
    __shared__ _Float16 Bs[128 * 64];   // X tile, 16 KB

    const int t    = threadIdx.x;
    const int w    = t >> 6;
    const int lane = t & 63;
    const int quad = lane >> 4;
    const int l16  = lane & 15;
    const int m0   = blockIdx.y * 64;   // gate-row tile (0..1536)
    const int n0   = blockIdx.x * 128;  // batch tile
    const int wm   = (w >> 1) * 32;
    const int wn   = (w & 1) * 64;
    const int lr   = lane >> 3;             // 0..7 row-in-8
    const int gq   = (lane & 7) ^ lr;       // logical granule this lane fetches

    floatx4 acc[2][4] = {};

    for (int k0 = 0; k0 < Kp; k0 += 64) {
        __syncthreads();
        {   // W: 4 chunks of 16 rows, one per wave
            const int cr = w * 16;
#pragma unroll
            for (int s = 0; s < 2; s++)
                gload_lds16(Wm + (size_t)(m0 + cr + s * 8 + lr) * Kp + k0 + gq * 8,
                            As + (cr + s * 8) * 64);
        }
#pragma unroll
        for (int j = 0; j < 2; j++) {   // X: 8 chunks of 16 rows
            const int cr = (j * 4 + w) * 16;
#pragma unroll
            for (int s = 0; s < 2; s++)
                gload_lds16(X + (size_t)(n0 + cr + s * 8 + lr) * Kp + k0 + gq * 8,
                            Bs + (cr + s * 8) * 64);
        }
        asm volatile("s_waitcnt vmcnt(0)" ::: "memory");
        __syncthreads();

#pragma unroll
        for (int h = 0; h < 2; h++) {
            half8 af[2], bf[4];
#pragma unroll
            for (int i = 0; i < 2; i++)
                af[i] = *(const half8*)(As + lds_off(wm + i * 16 + l16, h * 4 + quad));
#pragma unroll
            for (int i = 0; i < 4; i++)
                bf[i] = *(const half8*)(Bs + lds_off(wn + i * 16 + l16, h * 4 + quad));
#pragma unroll
            for (int mt = 0; mt < 2; mt++)
#pragma unroll
                for (int nt = 0; nt < 4; nt++)
                    acc[mt][nt] = __builtin_amdgcn_mfma_f32_16x16x32_f16(
                        af[mt], bf[nt], acc[mt][nt], 0, 0, 0);
        }
    }

#pragma unroll
    for (int mt = 0; mt < 2; mt++) {
        const int u = ((m0 + wm + mt * 16) >> 2) + quad;   // unit index, < 400
        const float bi  = bias[u];
        const float bff = bias[400 + u];
        const float bg  = bias[800 + u];
        const float bo  = bias[1200 + u];
#pragma unroll
        for (int nt = 0; nt < 4; nt++) {
            const int b = n0 + wn + nt * 16 + l16;         // batch index
            float gi = acc[mt][nt][0] + bi;
            float gf = acc[mt][nt][1] + bff;
            float gg = acc[mt][nt][2] + bg;
            float go = acc[mt][nt][3] + bo;
            float si = 1.f / (1.f + expf(-gi));
            float sf = 1.f / (1.f + expf(-gf));
            float so = 1.f / (1.f + expf(-go));
            float cn = sf * c_in[(size_t)b * LSTM_N + u] + si * tanhf(gg);
            float h  = so * tanhf(cn);
            if (fout) {
                fout[(size_t)b * LSTM_N + u] = h;
            } else {
                _Float16 hh = (_Float16)h;
                d1[(size_t)b * ld1 + u] = hh;
                if (d2) d2[(size_t)b * ld2 + u] = hh;
            }
        }
    }
}

// ---------------------------------------------------------------- plain GEMM
// Attention params: C[n_batch*32 + m] = sum_k Wa[m,k]*XA[n,k] + bias[m], m<30.
// Same 64x128/BK=64 structure; grid (32 batch-tiles, 1 row-tile).
__global__ __launch_bounds__(256) void gemm_plain(const _Float16* __restrict__ Wa,
                                                  const _Float16* __restrict__ XA,
                                                  const float* __restrict__ bias,
                                                  float* __restrict__ C, int Kp)
{
    __shared__ _Float16 As[64 * 64];
    __shared__ _Float16 Bs[128 * 64];

    const int t    = threadIdx.x;
    const int w    = t >> 6;
    const int lane = t & 63;
    const int quad = lane >> 4;
    const int l16  = lane & 15;
    const int n0   = blockIdx.x * 128;
    const int wm   = (w >> 1) * 32;
    const int wn   = (w & 1) * 64;
    const int lr   = lane >> 3;
    const int gq   = (lane & 7) ^ lr;

    floatx4 acc[2][4] = {};

    for (int k0 = 0; k0 < Kp; k0 += 64) {
        __syncthreads();
        {
            const int cr = w * 16;
#pragma unroll
            for (int s = 0; s < 2; s++)
                gload_lds16(Wa + (size_t)(cr + s * 8 + lr) * Kp + k0 + gq * 8,
                            As + (cr + s * 8) * 64);
        }
#pragma unroll
        for (int j = 0; j < 2; j++) {
            const int cr = (j * 4 + w) * 16;
#pragma unroll
            for (int s = 0; s < 2; s++)
                gload_lds16(XA + (size_t)(n0 + cr + s * 8 + lr) * Kp + k0 + gq * 8,
                            Bs + (cr + s * 8) * 64);
        }
        asm volatile("s_waitcnt vmcnt(0)" ::: "memory");
        __syncthreads();

#pragma unroll
        for (int h = 0; h < 2; h++) {
            half8 af[2], bf[4];
#pragma unroll
            for (int i = 0; i < 2; i++)
                af[i] = *(const half8*)(As + lds_off(wm + i * 16 + l16, h * 4 + quad));
#pragma unroll
            for (int i = 0; i < 4; i++)
                bf[i] = *(const half8*)(Bs + lds_off(wn + i * 16 + l16, h * 4 + quad));
#pragma unroll
            for (int mt = 0; mt < 2; mt++)
#pragma unroll
                for (int nt = 0; nt < 4; nt++)
                    acc[mt][nt] = __builtin_amdgcn_mfma_f32_16x16x32_f16(
                        af[mt], bf[nt], acc[mt][nt], 0, 0, 0);
        }
    }

#pragma unroll
    for (int mt = 0; mt < 2; mt++) {
#pragma unroll
        for (int r = 0; r < 4; r++) {
            const int m = wm + mt * 16 + quad * 4 + r;
            if (m >= 30) continue;
            const float bv = bias[m];
#pragma unroll
            for (int nt = 0; nt < 4; nt++) {
                const int b = n0 + wn + nt * 16 + l16;
                C[(size_t)b * 32 + m] = acc[mt][nt][r] + bv;
            }
        }
    }
}

// ---------------------------------------------------------------- attn phi+w
// wave = one batch row; 4 waves/block; grid B/4.
__global__ __launch_bounds__(256) void attn_phi(const float* __restrict__ AP,
                                                const float* __restrict__ kappa,
                                                const float* __restrict__ AV,
                                                const int* __restrict__ alen,
                                                _Float16* __restrict__ X2,
                                                _Float16* __restrict__ X3)
{
    __shared__ float prm[4][32];
    __shared__ float phi_s[4][CHARLEN];

    const int t = threadIdx.x;
    const int wave = t >> 6;
    const int lane = t & 63;
    const int b = blockIdx.x * 4 + wave;

    if (lane < 30) {
        float p  = AP[(size_t)b * 32 + lane];
        float sp = (p > 20.f) ? p : log1pf(expf(p));
        float v;
        if (lane < 10)      v = sp;                          // alpha
        else if (lane < 20) v = fmaxf(sp, 0.01f);            // beta
        else                v = kappa[(size_t)b * NATTN + (lane - 20)] + sp * (1.f / 25.f);
        prm[wave][lane] = v;
    }
    __syncthreads();

    const int len = alen[b];
    {
        int c = lane;
        float phi = 0.f;
#pragma unroll
        for (int j = 0; j < NATTN; j++) {
            float d = prm[wave][20 + j] - (float)c;
            phi += prm[wave][j] * expf(-d * d / prm[wave][10 + j]);
        }
        phi_s[wave][c] = (c < len) ? phi : 0.f;
    }
    __syncthreads();

    for (int v0 = 0; v0 < VOCAB; v0 += 64) {   // VOCAB=73 > 64 lanes
        const int v = v0 + lane;
        if (v < VOCAB) {
            const float* avb = AV + (size_t)b * CHARLEN * VOCAB + v;
            float s = 0.f;
            for (int c = 0; c < len; c++)      // len is wave-uniform
                s += phi_s[wave][c] * avb[(size_t)c * VOCAB];
            _Float16 wv = (_Float16)s;
            X2[(size_t)b * KP23 + 403 + v] = wv;
            X3[(size_t)b * KP23 + 403 + v] = wv;
        }
    }
}

// ---------------------------------------------------------------- launch
extern "C" void kernel_launch(void* const* d_in, const int* in_sizes, int n_in,
                              void* d_out, int out_size, void* d_ws, size_t ws_size,
                              hipStream_t stream)
{
    const float* inputs = (const float*)d_in[0];
    const float* h1     = (const float*)d_in[1];
    const float* c1     = (const float*)d_in[2];
    const float* h2     = (const float*)d_in[3];
    const float* c2     = (const float*)d_in[4];
    const float* h3     = (const float*)d_in[5];
    const float* c3     = (const float*)d_in[6];
    const float* kappa  = (const float*)d_in[7];
    const float* w_prev = (const float*)d_in[8];
    const float* AV     = (const float*)d_in[9];
    const int*   alen   = (const int*)d_in[10];
    const float* W_ih1  = (const float*)d_in[11];
    const float* W_hh1  = (const float*)d_in[12];
    const float* b1     = (const float*)d_in[13];
    const float* W_attn = (const float*)d_in[14];
    const float* b_attn = (const float*)d_in[15];
    const float* W_ih2  = (const float*)d_in[16];
    const float* W_hh2  = (const float*)d_in[17];
    const float* b2     = (const float*)d_in[18];
    const float* W_ih3  = (const float*)d_in[19];
    const float* W_hh3  = (const float*)d_in[20];
    const float* b3     = (const float*)d_in[21];
    float* out = (float*)d_out;

    char* p = (char*)d_ws;
    _Float16* X1 = (_Float16*)p; p += (size_t)B_SZ * KP1 * 2;
    _Float16* XA = (_Float16*)p; p += (size_t)B_SZ * KP1 * 2;   // attn input
    _Float16* X2 = (_Float16*)p; p += (size_t)B_SZ * KP23 * 2;
    _Float16* X3 = (_Float16*)p; p += (size_t)B_SZ * KP23 * 2;
    _Float16* W1 = (_Float16*)p; p += (size_t)NG * KP1 * 2;
    _Float16* W2 = (_Float16*)p; p += (size_t)NG * KP23 * 2;
    _Float16* W3 = (_Float16*)p; p += (size_t)NG * KP23 * 2;
    _Float16* Wa = (_Float16*)p; p += (size_t)64 * KP1 * 2;
    float* AP = (float*)p;                                       // B*32 fp32

    pack_wall<<<dim3(4, NG, 4), 256, 0, stream>>>(W_ih1, W_hh1, W_ih2, W_hh2,
                                                  W_ih3, W_hh3, W_attn,
                                                  W1, W2, W3, Wa);
    pack_x<<<dim3((KP1 + KP23 + 255) / 256, B_SZ), 256, 0, stream>>>(
        w_prev, inputs, h1, h2, h3, X1, XA, X2, X3);

    const dim3 fgrid(B_SZ / 128, NG / 64);   // 32 batch-tiles x 25 row-tiles

    // LSTM1: h1n -> XA h-region (attn input) + X2 cols 3..
    gemm_fused<<<fgrid, 256, 0, stream>>>(W1, X1, b1, c1,
                                          XA + 76, KP1, X2 + 3, KP23, nullptr, KP1);
    // attention params: AP[b,0:30] = Wa * XA[b] + b_attn
    gemm_plain<<<dim3(B_SZ / 128, 1), 256, 0, stream>>>(Wa, XA, b_attn, AP, KP1);
    // phi + einsum -> w into X2, X3
    attn_phi<<<B_SZ / 4, 256, 0, stream>>>(AP, kappa, AV, alen, X2, X3);
    // LSTM2: h2n -> X3 cols 3..
    gemm_fused<<<fgrid, 256, 0, stream>>>(W2, X2, b2, c2,
                                          X3 + 3, KP23, nullptr, 0, nullptr, KP23);
    // LSTM3: h3n -> out (fp32)
    gemm_fused<<<fgrid, 256, 0, stream>>>(W3, X3, b3, c3,
                                          nullptr, 0, nullptr, 0, out, KP23);
}